// Round 1
// 432.600 us; speedup vs baseline: 1.0865x; 1.0865x over previous
//
#include <hip/hip_runtime.h>

#define N_NODES 50000
#define N_EDGES 800000
#define E2      850000        // N_EDGES + N_NODES (self loops)
#define NODE_IN 32
#define EDGE_IN 16
#define EMB     128
#define GAT_IN  160           // NODE_IN + EMB
#define NLAYER  2
#define NGRAPH  8
#define NBLK    196           // ceil(N_NODES/256) for scan
#define NB32    1563          // ceil(N_NODES/32)
#define NB64    782           // ceil(N_NODES/64) for MFMA dense kernels

// gwt (fragment-ordered bf16 W^T) offsets in shorts
#define GWT_SRC0 0
#define GWT_SRC1 20480
#define GWT_OUT  40960
#define GWT_G    57344
#define GWT_TOT  73728

typedef short bf16x8 __attribute__((ext_vector_type(8)));
typedef float f32x4 __attribute__((ext_vector_type(4)));

// bf16 pack/unpack without hip_bf16.h (round-to-nearest-even)
__device__ __forceinline__ unsigned int f2bf(float f) {
    unsigned int u = __float_as_uint(f);
    return (u + 0x7FFFu + ((u >> 16) & 1u)) >> 16;
}
__device__ __forceinline__ float bf2f(unsigned int h) {
    return __uint_as_float(h << 16);
}
__device__ __forceinline__ unsigned int pack2bf(float a, float b) {
    return f2bf(a) | (f2bf(b) << 16);
}

// ---------------------------------------------------------------------------
__global__ void zero_kernel(float* __restrict__ p, int n) {
    int i = blockIdx.x * blockDim.x + threadIdx.x;
    int stride = gridDim.x * blockDim.x;
    for (; i < n; i += stride) p[i] = 0.f;
}

// ---------------------------------------------------------------------------
// count+rank (sharded histogram) fused with edge_attr mean accumulation.
// Blocks 0..511 additionally stream edge_attr and atomically add partial
// sums into meta[0..16). shard = blockIdx&3 == (e>>8)&3.
// ---------------------------------------------------------------------------
__global__ __launch_bounds__(256) void count_mean_kernel(const int* __restrict__ edge_index,
                                                         const float* __restrict__ edge_attr,
                                                         int* __restrict__ cnt4,
                                                         int* __restrict__ rank,
                                                         float* __restrict__ meta) {
    __shared__ float sm[16];
    int t = threadIdx.x;
    int e = blockIdx.x * 256 + t;
    if (e < E2) {
        int dst = (e < N_EDGES) ? edge_index[N_EDGES + e] : (e - N_EDGES);
        int shard = blockIdx.x & 3;
        rank[e] = atomicAdd(&cnt4[shard * N_NODES + dst], 1);
    }
    if (blockIdx.x < 512) {
        if (t < 16) sm[t] = 0.f;
        __syncthreads();
        int gid = blockIdx.x * 256 + t;
        int q = gid & 3;  // stride 512*256 is divisible by 4 -> q constant
        const float4* ea4 = (const float4*)edge_attr;
        float4 s = make_float4(0.f, 0.f, 0.f, 0.f);
        for (int j = gid; j < N_EDGES * 4; j += 512 * 256) {
            float4 v = ea4[j];
            s.x += v.x; s.y += v.y; s.z += v.z; s.w += v.w;
        }
        atomicAdd(&sm[q * 4 + 0], s.x);
        atomicAdd(&sm[q * 4 + 1], s.y);
        atomicAdd(&sm[q * 4 + 2], s.z);
        atomicAdd(&sm[q * 4 + 3], s.w);
        __syncthreads();
        if (t < 16) atomicAdd(&meta[t], sm[t]);
    }
}

// ---------------------------------------------------------------------------
// prep: finish mean; M[l][k][h]=sum_c W_edge[l,k,h*32+c]*att_edge[l,h,c]
// ---------------------------------------------------------------------------
__global__ void prep_kernel(const float* __restrict__ W_edge,
                            const float* __restrict__ att_edge,
                            float* __restrict__ meta) {
    int t = threadIdx.x;  // 128 threads
    if (t < EDGE_IN) meta[t] = meta[t] * (1.0f / (float)N_EDGES);
    __syncthreads();
    {
        int l = t >> 6, k = (t >> 2) & 15, h = t & 3;
        const float* w = W_edge + ((size_t)l * EDGE_IN + k) * EMB + h * 32;
        const float* a = att_edge + (size_t)l * EMB + h * 32;
        float acc = 0.f;
#pragma unroll
        for (int c = 0; c < 32; c++) acc += w[c] * a[c];
        meta[16 + (l * 16 + k) * 4 + h] = acc;
    }
    __syncthreads();
    if (t < 8) {
        int l = t >> 2, h = t & 3;
        float acc = 0.f;
#pragma unroll
        for (int k = 0; k < EDGE_IN; k++) acc += meta[k] * meta[16 + (l * 16 + k) * 4 + h];
        meta[144 + t] = acc;
    }
}

// ---------------------------------------------------------------------------
// prep_wt: pre-transpose W_src[0,1], W_out, W_g into bf16 fragment order:
// gwt[base + ((kc*8+nt)*64 + lane)*8 + j] = bf16(W[kc*32+quad*8+j][nt*16+l16])
// -> a wave's MFMA B-fragment is one coalesced 16B/lane global load.
// grid = 36 x 256 = 9216 groups exactly.
// ---------------------------------------------------------------------------
__global__ __launch_bounds__(256) void prep_wt_kernel(const float* __restrict__ Wsrc,
                                                      const float* __restrict__ Wout,
                                                      const float* __restrict__ Wg,
                                                      unsigned short* __restrict__ gwt) {
    int g = blockIdx.x * 256 + threadIdx.x;
    const float* Wm;
    int base, gg;
    if (g < 5120) {        // W_src layer 0/1, K=160: 2560 groups each
        int l = g / 2560;
        gg = g - l * 2560;
        Wm = Wsrc + (size_t)l * GAT_IN * EMB;
        base = l * 20480;
    } else if (g < 7168) { // W_out, K=128: 2048 groups
        gg = g - 5120;
        Wm = Wout;
        base = GWT_OUT;
    } else {               // W_g
        gg = g - 7168;
        Wm = Wg;
        base = GWT_G;
    }
    int lane = gg & 63, tmp = gg >> 6;
    int nt = tmp & 7, kc = tmp >> 3;
    int quad = lane >> 4, l16 = lane & 15;
    int col = nt * 16 + l16, k0 = kc * 32 + quad * 8;
    unsigned int u[4];
#pragma unroll
    for (int j = 0; j < 4; j++)
        u[j] = pack2bf(Wm[(size_t)(k0 + 2 * j) * EMB + col], Wm[(size_t)(k0 + 2 * j + 1) * EMB + col]);
    *(uint4*)(gwt + base + (size_t)gg * 8) = make_uint4(u[0], u[1], u[2], u[3]);
}

// ---------------------------------------------------------------------------
// hierarchical scan; scan3 emits per-shard bases
// ---------------------------------------------------------------------------
__global__ __launch_bounds__(256) void scan1_kernel(const int* __restrict__ cnt4,
                                                    int* __restrict__ bsum) {
    __shared__ int sm[256];
    int t = threadIdx.x;
    int i = blockIdx.x * 256 + t;
    int tot = 0;
    if (i < N_NODES) {
#pragma unroll
        for (int s = 0; s < 4; s++) tot += cnt4[s * N_NODES + i];
    }
    sm[t] = tot;
    __syncthreads();
#pragma unroll
    for (int d = 128; d >= 1; d >>= 1) {
        if (t < d) sm[t] += sm[t + d];
        __syncthreads();
    }
    if (t == 0) bsum[blockIdx.x] = sm[0];
}

__global__ __launch_bounds__(256) void scan2_kernel(const int* __restrict__ bsum,
                                                    int* __restrict__ bbase) {
    __shared__ int sm[256];
    int t = threadIdx.x;
    int v = (t < NBLK) ? bsum[t] : 0;
    sm[t] = v;
    __syncthreads();
#pragma unroll
    for (int d = 1; d < 256; d <<= 1) {
        int u = (t >= d) ? sm[t - d] : 0;
        __syncthreads();
        sm[t] += u;
        __syncthreads();
    }
    if (t < NBLK) bbase[t] = sm[t] - v;  // exclusive
}

__global__ __launch_bounds__(256) void scan3_kernel(const int* __restrict__ bbase,
                                                    const int* __restrict__ cnt4,
                                                    int* __restrict__ off,
                                                    int* __restrict__ shard_base) {
    __shared__ int sm[256];
    int t = threadIdx.x;
    int i = blockIdx.x * 256 + t;
    int c[4] = {0, 0, 0, 0};
    int tot = 0;
    if (i < N_NODES) {
#pragma unroll
        for (int s = 0; s < 4; s++) {
            c[s] = cnt4[s * N_NODES + i];
            tot += c[s];
        }
    }
    sm[t] = tot;
    __syncthreads();
#pragma unroll
    for (int d = 1; d < 256; d <<= 1) {
        int u = (t >= d) ? sm[t - d] : 0;
        __syncthreads();
        sm[t] += u;
        __syncthreads();
    }
    if (i < N_NODES) {
        int base = bbase[blockIdx.x] + sm[t] - tot;  // exclusive
        off[i] = base;
        int4 sb;
        sb.x = base;            base += c[0];
        sb.y = base;            base += c[1];
        sb.z = base;            base += c[2];
        sb.w = base;
        *(int4*)(shard_base + i * 4) = sb;
        if (i == N_NODES - 1) off[N_NODES] = E2;
    }
}

// ---------------------------------------------------------------------------
// fill_perm: minimal 8B scatter {src, e} -> pos (atomic-free).
// Replaces the old 36B/edge scatter that had 2.6x write amplification.
// ---------------------------------------------------------------------------
__global__ __launch_bounds__(256) void fill_perm_kernel(const int* __restrict__ edge_index,
                                                        const int* __restrict__ rank,
                                                        const int* __restrict__ shard_base,
                                                        int* __restrict__ perm) {
    int e = blockIdx.x * 256 + threadIdx.x;
    if (e >= E2) return;
    int src, dst;
    if (e < N_EDGES) {
        src = edge_index[e];
        dst = edge_index[N_EDGES + e];
    } else {
        src = dst = e - N_EDGES;
    }
    int shard = (e >> 8) & 3;  // matches count_mean's blockIdx&3
    int pos = shard_base[dst * 4 + shard] + rank[e];
    ((int2*)perm)[pos] = make_int2(src, e);
}

// ---------------------------------------------------------------------------
// compute_ae: stream positions in order; gather edge_attr[e] (one full 64B
// line per edge, no amplification); write csr_src + csr_ae coalesced.
// ---------------------------------------------------------------------------
__global__ __launch_bounds__(256) void compute_ae_kernel(const int* __restrict__ perm,
                                                         const float* __restrict__ edge_attr,
                                                         const float* __restrict__ meta,
                                                         int* __restrict__ csr_src,
                                                         float* __restrict__ csr_ae0,
                                                         float* __restrict__ csr_ae1) {
    __shared__ float Ml[128];
    __shared__ float loop_ae[8];
    int t = threadIdx.x;
    if (t < 128) Ml[t] = meta[16 + t];
    if (t < 8) loop_ae[t] = meta[144 + t];
    __syncthreads();
    int p = blockIdx.x * 256 + t;
    if (p >= E2) return;
    int2 pe = ((const int2*)perm)[p];
    int src = pe.x, e = pe.y;
    csr_src[p] = src;
    float ae[2][4];
    if (e < N_EDGES) {
        const float4* r4 = (const float4*)(edge_attr + (size_t)e * EDGE_IN);
#pragma unroll
        for (int l = 0; l < 2; l++)
#pragma unroll
            for (int hh = 0; hh < 4; hh++) ae[l][hh] = 0.f;
#pragma unroll
        for (int q = 0; q < 4; q++) {
            float4 v = r4[q];
#pragma unroll
            for (int l = 0; l < 2; l++) {
                const float* M = Ml + l * 64;
#pragma unroll
                for (int hh = 0; hh < 4; hh++) {
                    ae[l][hh] += v.x * M[(4 * q + 0) * 4 + hh] + v.y * M[(4 * q + 1) * 4 + hh] +
                                 v.z * M[(4 * q + 2) * 4 + hh] + v.w * M[(4 * q + 3) * 4 + hh];
                }
            }
        }
    } else {
#pragma unroll
        for (int l = 0; l < 2; l++)
#pragma unroll
            for (int hh = 0; hh < 4; hh++) ae[l][hh] = loop_ae[l * 4 + hh];
    }
    *(float4*)(csr_ae0 + (size_t)p * 4) = make_float4(ae[0][0], ae[0][1], ae[0][2], ae[0][3]);
    *(float4*)(csr_ae1 + (size_t)p * 4) = make_float4(ae[1][0], ae[1][1], ae[1][2], ae[1][3]);
}

// ---------------------------------------------------------------------------
// input proj: h = relu(x @ W_in + b) -> h_bf (packed bf16); also emits x_bf
// ---------------------------------------------------------------------------
__global__ __launch_bounds__(256) void input_proj_kernel(const float* __restrict__ x,
                                                         const float* __restrict__ W,
                                                         const float* __restrict__ b,
                                                         unsigned int* __restrict__ h_bf,
                                                         unsigned int* __restrict__ x_bf) {
    __shared__ float inp[32][NODE_IN];  // 4 KB
    int t = threadIdx.x;
    int n0 = blockIdx.x * 32;
    for (int i = t; i < 32 * NODE_IN; i += 256) {
        int r = i >> 5, c = i & 31;
        int n = min(n0 + r, N_NODES - 1);
        inp[r][c] = x[(size_t)n * NODE_IN + c];
    }
    __syncthreads();
    // x_bf: 32 nodes x 16 packed pairs
    for (int i = t; i < 32 * 16; i += 256) {
        int r = i >> 4, c = i & 15;
        int n = n0 + r;
        if (n < N_NODES) x_bf[(size_t)n * 16 + c] = pack2bf(inp[r][2 * c], inp[r][2 * c + 1]);
    }
    int wave = t >> 6, lane = t & 63;
    int c0 = lane * 2, c1 = c0 + 1;
    const float2* W2 = (const float2*)W;
    float acc[8][2];
#pragma unroll
    for (int j = 0; j < 8; j++) { acc[j][0] = b[c0]; acc[j][1] = b[c1]; }
#pragma unroll 2
    for (int k4 = 0; k4 < NODE_IN / 4; k4++) {
        float4 v[8];
#pragma unroll
        for (int j = 0; j < 8; j++) v[j] = *(const float4*)&inp[wave * 8 + j][k4 * 4];
#pragma unroll
        for (int kk = 0; kk < 4; kk++) {
            float2 w = W2[(k4 * 4 + kk) * 64 + lane];
#pragma unroll
            for (int j = 0; j < 8; j++) {
                float vv = (&v[j].x)[kk];
                acc[j][0] += vv * w.x;
                acc[j][1] += vv * w.y;
            }
        }
    }
#pragma unroll
    for (int j = 0; j < 8; j++) {
        int n = n0 + wave * 8 + j;
        if (n < N_NODES)
            h_bf[(size_t)n * 64 + lane] = pack2bf(fmaxf(acc[j][0], 0.f), fmaxf(acc[j][1], 0.f));
    }
}

// ---------------------------------------------------------------------------
// MFMA dense kernel: C[64 nodes][128] = A @ W. A from bf16-packed global
// (x_bf/h_bf), B from pre-transposed fragment-ordered gwt (global, L2-hot).
// NO W staging, NO transpose, one barrier before epilogue.
// A-chunk offset is in UINTS: 16 uints = 32 bf16 per K-chunk (r9 bug: was 8).
// ---------------------------------------------------------------------------
template <int K, int MODE>
__global__ __launch_bounds__(256) void dense_mfma_kernel(
    const unsigned int* __restrict__ xbf, const unsigned int* __restrict__ hbf,
    const unsigned short* __restrict__ gwt, const float* __restrict__ bias,
    const float* __restrict__ v1, const float* __restrict__ v2,
    const int* __restrict__ batch,
    unsigned int* __restrict__ xs_out, float* __restrict__ a_s, float* __restrict__ a_d,
    float* __restrict__ out_nodes, float* __restrict__ gsum, float* __restrict__ gcnt) {
    constexpr int CLS = 132;
    __shared__ __align__(16) float cl[64 * CLS];            // 33 KB
    __shared__ float red[(MODE != 0) ? 64 : 1][8];
    __shared__ float locw[(MODE == 2) ? 4 : 1][2][EMB];
    __shared__ int bids[(MODE == 2) ? 64 : 1];

    int t = threadIdx.x;
    int n0 = blockIdx.x * 64;
    if (MODE == 2 && t < 64) bids[t] = batch[min(n0 + t, N_NODES - 1)];

    int wave = t >> 6, lane = t & 63;
    int quad = lane >> 4, l16 = lane & 15;
    int arow = min(n0 + wave * 16 + l16, N_NODES - 1);
    const bf16x8* B = (const bf16x8*)gwt;
    f32x4 acc[8];
#pragma unroll
    for (int i = 0; i < 8; i++) acc[i] = (f32x4){0.f, 0.f, 0.f, 0.f};
#pragma unroll
    for (int kc = 0; kc < K / 32; kc++) {
        bf16x8 af;
        if (MODE == 0 && kc == 0) {
            af = *(const bf16x8*)(xbf + (size_t)arow * 16 + quad * 4);
        } else {
            int hk = ((MODE == 0) ? (kc - 1) : kc) * 16;  // UINT units (32 bf16/chunk)
            af = *(const bf16x8*)(hbf + (size_t)arow * 64 + hk + quad * 4);
        }
#pragma unroll
        for (int nt = 0; nt < 8; nt++) {
            bf16x8 bfv = B[(kc * 8 + nt) * 64 + lane];
            acc[nt] = __builtin_amdgcn_mfma_f32_16x16x32_bf16(af, bfv, acc[nt], 0, 0, 0);
        }
    }
#pragma unroll
    for (int nt = 0; nt < 8; nt++) {
#pragma unroll
        for (int i = 0; i < 4; i++) {
            int r = wave * 16 + quad * 4 + i;  // C: row = quad*4+reg, col = l16
            cl[r * CLS + nt * 16 + l16] = acc[nt][i];
        }
    }
    __syncthreads();

    // row-wise epilogue: thread t -> node r = t>>2, part p = t&3 (32 cols)
    int p = t & 3, r = t >> 2;
    int n = n0 + r;
    const float4* c4 = (const float4*)(cl + r * CLS + p * 32);

    if (MODE == 0) {
        const float4* s4 = (const float4*)(v1 + p * 32);
        const float4* d4 = (const float4*)(v2 + p * 32);
        if (n < N_NODES) {
            float s_ = 0.f, d_ = 0.f;
#pragma unroll
            for (int i = 0; i < 8; i++) {
                float4 cv = c4[i], sv = s4[i], dv = d4[i];
                s_ += cv.x * sv.x + cv.y * sv.y + cv.z * sv.z + cv.w * sv.w;
                d_ += cv.x * dv.x + cv.y * dv.y + cv.z * dv.z + cv.w * dv.w;
                uint2 pk = make_uint2(pack2bf(cv.x, cv.y), pack2bf(cv.z, cv.w));
                *(uint2*)(xs_out + (size_t)n * 64 + p * 16 + 2 * i) = pk;
            }
            a_s[(size_t)n * 4 + p] = s_;
            a_d[(size_t)n * 4 + p] = d_;
        }
    } else {
        const float4* b4 = (const float4*)(bias + p * 32);
        float vals[32];
        float s_ = 0.f, q_ = 0.f;
#pragma unroll
        for (int i = 0; i < 8; i++) {
            float4 cv = c4[i], bv = b4[i];
            float w0 = fmaxf(cv.x + bv.x, 0.f), w1 = fmaxf(cv.y + bv.y, 0.f);
            float w2 = fmaxf(cv.z + bv.z, 0.f), w3 = fmaxf(cv.w + bv.w, 0.f);
            vals[4 * i] = w0; vals[4 * i + 1] = w1; vals[4 * i + 2] = w2; vals[4 * i + 3] = w3;
            s_ += w0 + w1 + w2 + w3;
            q_ += w0 * w0 + w1 * w1 + w2 * w2 + w3 * w3;
        }
        red[r][p] = s_;
        red[r][4 + p] = q_;
        __syncthreads();
        float sm = red[r][0] + red[r][1] + red[r][2] + red[r][3];
        float sq = red[r][4] + red[r][5] + red[r][6] + red[r][7];
        float mean = sm * (1.f / EMB);
        float var = sq * (1.f / EMB) - mean * mean;
        float rstd = rsqrtf(var + 1e-5f);
        const float4* g4 = (const float4*)(v1 + p * 32);
        const float4* be4 = (const float4*)(v2 + p * 32);
#pragma unroll
        for (int i = 0; i < 8; i++) {
            float4 gv = g4[i], bv = be4[i];
            vals[4 * i]     = (vals[4 * i]     - mean) * rstd * gv.x + bv.x;
            vals[4 * i + 1] = (vals[4 * i + 1] - mean) * rstd * gv.y + bv.y;
            vals[4 * i + 2] = (vals[4 * i + 2] - mean) * rstd * gv.z + bv.z;
            vals[4 * i + 3] = (vals[4 * i + 3] - mean) * rstd * gv.w + bv.w;
        }
        if (MODE == 1) {
            if (n < N_NODES) {
                float* op = out_nodes + (size_t)n * EMB + p * 32;
#pragma unroll
                for (int i = 0; i < 8; i++)
                    *(float4*)(op + 4 * i) = make_float4(vals[4 * i], vals[4 * i + 1],
                                                         vals[4 * i + 2], vals[4 * i + 3]);
            }
        } else {
            int nvalid = min(64, N_NODES - n0);
            int bmin = bids[0], bmax = bids[nvalid - 1];
            int bid = bids[r];
            bool inA = (bid == bmin) && (n < N_NODES);
            bool inB = (bid == bmax) && (bmax != bmin) && (n < N_NODES);
            if (n < N_NODES && bid != bmin && bid != bmax) {
#pragma unroll
                for (int i = 0; i < 32; i++)
                    atomicAdd(&gsum[(size_t)bid * EMB + p * 32 + i], vals[i]);
            }
#pragma unroll
            for (int g = 0; g < 2; g++) {
                bool m = g ? inB : inA;
#pragma unroll
                for (int i = 0; i < 32; i++) {
                    float v = m ? vals[i] : 0.f;
                    v += __shfl_xor(v, 4, 64);
                    v += __shfl_xor(v, 8, 64);
                    v += __shfl_xor(v, 16, 64);
                    v += __shfl_xor(v, 32, 64);
                    if ((lane >> 2) == 0) locw[wave][g][(lane & 3) * 32 + i] = v;
                }
            }
            __syncthreads();
            if (t < 128) {
                float sA = locw[0][0][t] + locw[1][0][t] + locw[2][0][t] + locw[3][0][t];
                atomicAdd(&gsum[(size_t)bmin * EMB + t], sA);
                if (bmax != bmin) {
                    float sB = locw[0][1][t] + locw[1][1][t] + locw[2][1][t] + locw[3][1][t];
                    atomicAdd(&gsum[(size_t)bmax * EMB + t], sB);
                }
            } else if (t == 255) {
                int cA = 0, cB = 0;
                for (int rr = 0; rr < nvalid; rr++) {
                    int bb = bids[rr];
                    if (bb == bmin) cA++;
                    else if (bb == bmax) cB++;
                    else atomicAdd(&gcnt[bb], 1.f);
                }
                atomicAdd(&gcnt[bmin], (float)cA);
                if (bmax != bmin && cB > 0) atomicAdd(&gcnt[bmax], (float)cB);
            }
        }
    }
}

// ---------------------------------------------------------------------------
// gather: wave per node; 16 lanes per edge, 4 edge-groups, 2-deep unroll
// (8 edges in flight). Each lane loads a uint4 (8 bf16 cols) of xs[src].
// Cross-group combine via shfl_xor(16/32); fused /denom + bias + LN + ELU.
// Zero atomics.
// ---------------------------------------------------------------------------
__global__ __launch_bounds__(256) void gat_gather_kernel(const int* __restrict__ off,
                                                         const int* __restrict__ csr_src,
                                                         const float* __restrict__ csr_ae,
                                                         const unsigned int* __restrict__ xs,
                                                         const float* __restrict__ a_s,
                                                         const float* __restrict__ a_d,
                                                         const float* __restrict__ bias_l,
                                                         const float* __restrict__ gamma_l,
                                                         const float* __restrict__ beta_l,
                                                         unsigned int* __restrict__ h_bf) {
    int t = threadIdx.x, wave = t >> 6, lane = t & 63;
    int n = blockIdx.x * 4 + wave;  // grid = N/4 exactly
    int g = lane >> 4, l16 = lane & 15;
    int h = l16 >> 2;               // head for cols [l16*8, l16*8+8)
    float ad = a_d[(size_t)n * 4 + h];
    int p0 = __builtin_amdgcn_readfirstlane(off[n]);
    int p1 = __builtin_amdgcn_readfirstlane(off[n + 1]);
    int plast = p1 - 1;             // deg >= 1 always (self loop)
    float den = 0.f;
    float acc[8];
#pragma unroll
    for (int j = 0; j < 8; j++) acc[j] = 0.f;

    for (int pb = p0; pb < p1; pb += 8) {
        int pA = pb + g, pB = pb + 4 + g;
        int iA = min(pA, plast), iB = min(pB, plast);
        int sA = csr_src[iA], sB = csr_src[iB];
        float aeA = csr_ae[(size_t)iA * 4 + h];
        float aeB = csr_ae[(size_t)iB * 4 + h];
        float asA = a_s[(size_t)sA * 4 + h];
        float asB = a_s[(size_t)sB * 4 + h];
        uint4 xA = *(const uint4*)(xs + (size_t)sA * 64 + l16 * 4);
        uint4 xB = *(const uint4*)(xs + (size_t)sB * 64 + l16 * 4);
        float alA = asA + ad + aeA;
        alA = alA > 0.f ? alA : 0.2f * alA;
        float exA = (pA <= plast) ? __expf(alA) : 0.f;
        float alB = asB + ad + aeB;
        alB = alB > 0.f ? alB : 0.2f * alB;
        float exB = (pB <= plast) ? __expf(alB) : 0.f;
        den += exA + exB;
        unsigned int u;
        u = xA.x; acc[0] += exA * bf2f(u & 0xFFFFu); acc[1] += exA * bf2f(u >> 16);
        u = xA.y; acc[2] += exA * bf2f(u & 0xFFFFu); acc[3] += exA * bf2f(u >> 16);
        u = xA.z; acc[4] += exA * bf2f(u & 0xFFFFu); acc[5] += exA * bf2f(u >> 16);
        u = xA.w; acc[6] += exA * bf2f(u & 0xFFFFu); acc[7] += exA * bf2f(u >> 16);
        u = xB.x; acc[0] += exB * bf2f(u & 0xFFFFu); acc[1] += exB * bf2f(u >> 16);
        u = xB.y; acc[2] += exB * bf2f(u & 0xFFFFu); acc[3] += exB * bf2f(u >> 16);
        u = xB.z; acc[4] += exB * bf2f(u & 0xFFFFu); acc[5] += exB * bf2f(u >> 16);
        u = xB.w; acc[6] += exB * bf2f(u & 0xFFFFu); acc[7] += exB * bf2f(u >> 16);
    }
    // combine the 4 edge-groups (cols identical across groups)
#pragma unroll
    for (int j = 0; j < 8; j++) {
        acc[j] += __shfl_xor(acc[j], 16, 64);
        acc[j] += __shfl_xor(acc[j], 32, 64);
    }
    den += __shfl_xor(den, 16, 64);
    den += __shfl_xor(den, 32, 64);

    float dinv = 1.0f / (den + 1e-16f);
    int c0 = l16 * 8;
    const float4* b4 = (const float4*)(bias_l + c0);
    float4 bv0 = b4[0], bv1 = b4[1];
    float v[8];
    v[0] = acc[0] * dinv + bv0.x; v[1] = acc[1] * dinv + bv0.y;
    v[2] = acc[2] * dinv + bv0.z; v[3] = acc[3] * dinv + bv0.w;
    v[4] = acc[4] * dinv + bv1.x; v[5] = acc[5] * dinv + bv1.y;
    v[6] = acc[6] * dinv + bv1.z; v[7] = acc[7] * dinv + bv1.w;
    float sm = 0.f, sq = 0.f;
#pragma unroll
    for (int j = 0; j < 8; j++) { sm += v[j]; sq += v[j] * v[j]; }
#pragma unroll
    for (int o = 1; o <= 8; o <<= 1) {
        sm += __shfl_xor(sm, o, 64);
        sq += __shfl_xor(sq, o, 64);
    }
    float mean = sm * (1.f / EMB);
    float var = sq * (1.f / EMB) - mean * mean;
    float rstd = rsqrtf(var + 1e-5f);
    const float4* g4 = (const float4*)(gamma_l + c0);
    const float4* be4 = (const float4*)(beta_l + c0);
    float4 gv0 = g4[0], gv1 = g4[1], bev0 = be4[0], bev1 = be4[1];
    float y[8];
    y[0] = (v[0] - mean) * rstd * gv0.x + bev0.x;
    y[1] = (v[1] - mean) * rstd * gv0.y + bev0.y;
    y[2] = (v[2] - mean) * rstd * gv0.z + bev0.z;
    y[3] = (v[3] - mean) * rstd * gv0.w + bev0.w;
    y[4] = (v[4] - mean) * rstd * gv1.x + bev1.x;
    y[5] = (v[5] - mean) * rstd * gv1.y + bev1.y;
    y[6] = (v[6] - mean) * rstd * gv1.z + bev1.z;
    y[7] = (v[7] - mean) * rstd * gv1.w + bev1.w;
#pragma unroll
    for (int j = 0; j < 8; j++) y[j] = y[j] > 0.f ? y[j] : __expf(y[j]) - 1.f;  // elu
    if (g == 0) {
        uint4 o4;
        o4.x = pack2bf(y[0], y[1]);
        o4.y = pack2bf(y[2], y[3]);
        o4.z = pack2bf(y[4], y[5]);
        o4.w = pack2bf(y[6], y[7]);
        *(uint4*)(h_bf + (size_t)n * 64 + l16 * 4) = o4;
    }
}

__global__ void graph_out_kernel(const float* __restrict__ gsum, const float* __restrict__ gcnt,
                                 float* __restrict__ out) {
    int i = blockIdx.x * blockDim.x + threadIdx.x;
    if (i >= NGRAPH * EMB) return;
    int b = i >> 7;
    float c = fmaxf(gcnt[b], 1.f);
    out[(size_t)N_NODES * EMB + i] = gsum[i] / c;
}

// ---------------------------------------------------------------------------
extern "C" void kernel_launch(void* const* d_in, const int* in_sizes, int n_in,
                              void* d_out, int out_size, void* d_ws, size_t ws_size,
                              hipStream_t stream) {
    (void)in_sizes; (void)n_in; (void)out_size; (void)ws_size;
    const float* x         = (const float*)d_in[0];
    const float* edge_attr = (const float*)d_in[1];
    const float* W_in      = (const float*)d_in[2];
    const float* b_in      = (const float*)d_in[3];
    const float* W_src     = (const float*)d_in[4];
    const float* W_edge    = (const float*)d_in[5];
    const float* att_src   = (const float*)d_in[6];
    const float* att_dst   = (const float*)d_in[7];
    const float* att_edge  = (const float*)d_in[8];
    const float* gat_bias  = (const float*)d_in[9];
    const float* ln_gamma  = (const float*)d_in[10];
    const float* ln_beta   = (const float*)d_in[11];
    const float* W_out     = (const float*)d_in[12];
    const float* b_out     = (const float*)d_in[13];
    const float* ln_og     = (const float*)d_in[14];
    const float* ln_ob     = (const float*)d_in[15];
    const float* W_g       = (const float*)d_in[16];
    const float* b_g       = (const float*)d_in[17];
    const float* g_gamma   = (const float*)d_in[18];
    const float* g_beta    = (const float*)d_in[19];
    const int* edge_index  = (const int*)d_in[20];
    const int* batch       = (const int*)d_in[21];
    float* out = (float*)d_out;

    float* ws              = (float*)d_ws;
    unsigned int* h_bf     = (unsigned int*)ws;               // N*64
    unsigned int* xs       = h_bf + (size_t)N_NODES * 64;     // N*64
    unsigned int* x_bf     = xs + (size_t)N_NODES * 64;       // N*16
    float* a_s             = (float*)(x_bf + (size_t)N_NODES * 16);  // N*4
    float* a_d             = a_s + (size_t)N_NODES * 4;       // N*4
    float* csr_ae          = a_d + (size_t)N_NODES * 4;       // 2*E2*4
    unsigned short* gwt    = (unsigned short*)(csr_ae + (size_t)2 * E2 * 4);  // 73728 shorts
    float* meta            = (float*)(gwt + GWT_TOT);         // 152
    float* gsum            = meta + 152;                      // 1024
    float* gcnt            = gsum + NGRAPH * EMB;             // 8
    int*   cnt4            = (int*)(gcnt + NGRAPH);           // 4*N
    int*   off             = cnt4 + 4 * N_NODES;              // N+1
    int*   shard_base      = off + N_NODES + 1;               // 4*N
    int*   rank            = shard_base + 4 * N_NODES;        // E2
    int*   csr_src         = rank + E2;                       // E2
    int*   bsum            = csr_src + E2;                    // NBLK
    int*   bbase           = bsum + NBLK;                     // NBLK
    // perm (int2[E2] = 6.8MB) aliases xs: xs is first written by dense layer 0,
    // which runs after compute_ae has consumed perm. 16B-aligned (word 3.2M).
    int*   perm            = (int*)xs;
    // total ~16.6M words = 66.3 MB (< 75.8 proven in round 8)

    const int EB = (E2 + 255) / 256;  // 3321

    zero_kernel<<<256, 256, 0, stream>>>(meta, 152 + NGRAPH * EMB + NGRAPH + 4 * N_NODES);
    count_mean_kernel<<<EB, 256, 0, stream>>>(edge_index, edge_attr, cnt4, rank, meta);
    prep_kernel<<<1, 128, 0, stream>>>(W_edge, att_edge, meta);
    prep_wt_kernel<<<36, 256, 0, stream>>>(W_src, W_out, W_g, gwt);
    input_proj_kernel<<<NB32, 256, 0, stream>>>(x, W_in, b_in, h_bf, x_bf);

    scan1_kernel<<<NBLK, 256, 0, stream>>>(cnt4, bsum);
    scan2_kernel<<<1, 256, 0, stream>>>(bsum, bbase);
    scan3_kernel<<<NBLK, 256, 0, stream>>>(bbase, cnt4, off, shard_base);
    fill_perm_kernel<<<EB, 256, 0, stream>>>(edge_index, rank, shard_base, perm);
    compute_ae_kernel<<<EB, 256, 0, stream>>>(perm, edge_attr, meta,
                                              csr_src, csr_ae, csr_ae + (size_t)E2 * 4);

    for (int l = 0; l < NLAYER; l++) {
        dense_mfma_kernel<GAT_IN, 0><<<NB64, 256, 0, stream>>>(
            x_bf, h_bf, gwt + (l ? GWT_SRC1 : GWT_SRC0), nullptr,
            att_src + (size_t)l * EMB, att_dst + (size_t)l * EMB, nullptr,
            xs, a_s, a_d, nullptr, nullptr, nullptr);
        gat_gather_kernel<<<N_NODES / 4, 256, 0, stream>>>(
            off, csr_src, csr_ae + (size_t)l * E2 * 4, xs, a_s, a_d,
            gat_bias + (size_t)l * EMB, ln_gamma + (size_t)l * EMB,
            ln_beta + (size_t)l * EMB, h_bf);
    }

    dense_mfma_kernel<EMB, 1><<<NB64, 256, 0, stream>>>(
        nullptr, h_bf, gwt + GWT_OUT, b_out, ln_og, ln_ob, nullptr,
        nullptr, nullptr, nullptr, out, nullptr, nullptr);
    dense_mfma_kernel<EMB, 2><<<NB64, 256, 0, stream>>>(
        nullptr, h_bf, gwt + GWT_G, b_g, g_gamma, g_beta, batch,
        nullptr, nullptr, nullptr, nullptr, gsum, gcnt);
    graph_out_kernel<<<4, 256, 0, stream>>>(gsum, gcnt, out);
}

// Round 2
// 421.802 us; speedup vs baseline: 1.1143x; 1.0256x over previous
//
#include <hip/hip_runtime.h>

#define N_NODES 50000
#define N_EDGES 800000
#define E2      850000        // N_EDGES + N_NODES (self loops)
#define NODE_IN 32
#define EDGE_IN 16
#define EMB     128
#define GAT_IN  160           // NODE_IN + EMB
#define NLAYER  2
#define NGRAPH  8
#define NBLK    196           // ceil(N_NODES/256) for scan
#define NB32    1563          // ceil(N_NODES/32)
#define NB64    782           // ceil(N_NODES/64) for MFMA dense kernels
#define EB      3321          // ceil(E2/256)

// gwt (fragment-ordered bf16 W^T) offsets in shorts
#define GWT_SRC0 0
#define GWT_SRC1 20480
#define GWT_OUT  40960
#define GWT_G    57344
#define GWT_TOT  73728

typedef short bf16x8 __attribute__((ext_vector_type(8)));
typedef float f32x4 __attribute__((ext_vector_type(4)));

// bf16 pack/unpack without hip_bf16.h (round-to-nearest-even)
__device__ __forceinline__ unsigned int f2bf(float f) {
    unsigned int u = __float_as_uint(f);
    return (u + 0x7FFFu + ((u >> 16) & 1u)) >> 16;
}
__device__ __forceinline__ float bf2f(unsigned int h) {
    return __uint_as_float(h << 16);
}
__device__ __forceinline__ unsigned int pack2bf(float a, float b) {
    return f2bf(a) | (f2bf(b) << 16);
}

// ---------------------------------------------------------------------------
__global__ void zero_kernel(float* __restrict__ p, int n) {
    int i = blockIdx.x * blockDim.x + threadIdx.x;
    int stride = gridDim.x * blockDim.x;
    for (; i < n; i += stride) p[i] = 0.f;
}

// ---------------------------------------------------------------------------
// mega kernel: fuses three independent phases so streaming/VALU work hides
// under the atomic-latency-bound count phase.
//   blocks [0, EB):          count+rank (8 XCD-affine shards) + edge_attr mean
//   blocks [EB, EB+NB32):    input projection (x -> h_bf, x_bf)
//   blocks [EB+NB32, +36):   weight pre-transpose into gwt
// shard = blockIdx&7: consecutive blocks round-robin across the 8 XCDs, so
// each 200KB shard table is touched by (mostly) one XCD -> atomics stay local
// to that XCD's L2 instead of bouncing through cross-XCD coherence.
// ---------------------------------------------------------------------------
__global__ __launch_bounds__(256) void mega_kernel(
    const int* __restrict__ edge_index, const float* __restrict__ edge_attr,
    const float* __restrict__ x, const float* __restrict__ W_in,
    const float* __restrict__ b_in,
    const float* __restrict__ Wsrc, const float* __restrict__ Wout,
    const float* __restrict__ Wg,
    int* __restrict__ cnt8, int* __restrict__ rank, float* __restrict__ meta,
    unsigned int* __restrict__ h_bf, unsigned int* __restrict__ x_bf,
    unsigned short* __restrict__ gwt) {
    __shared__ float smem[32 * NODE_IN];  // 4 KB union
    int b = blockIdx.x, t = threadIdx.x;

    if (b < EB) {
        // ---- count + rank (XCD-affine shards) ----
        int e = b * 256 + t;
        if (e < E2) {
            int dst = (e < N_EDGES) ? edge_index[N_EDGES + e] : (e - N_EDGES);
            int shard = b & 7;  // == (e>>8)&7
            rank[e] = atomicAdd(&cnt8[shard * N_NODES + dst], 1);
        }
        // ---- edge_attr mean (first 512 blocks only: bounds same-line atomics) ----
        if (b < 512) {
            if (t < 16) smem[t] = 0.f;
            __syncthreads();
            int gid = b * 256 + t;
            int q = gid & 3;  // stride 512*256 divisible by 4 -> q constant
            const float4* ea4 = (const float4*)edge_attr;
            float4 s = make_float4(0.f, 0.f, 0.f, 0.f);
            for (int j = gid; j < N_EDGES * 4; j += 512 * 256) {
                float4 v = ea4[j];
                s.x += v.x; s.y += v.y; s.z += v.z; s.w += v.w;
            }
            atomicAdd(&smem[q * 4 + 0], s.x);
            atomicAdd(&smem[q * 4 + 1], s.y);
            atomicAdd(&smem[q * 4 + 2], s.z);
            atomicAdd(&smem[q * 4 + 3], s.w);
            __syncthreads();
            if (t < 16) atomicAdd(&meta[t], smem[t]);
        }
    } else if (b < EB + NB32) {
        // ---- input projection: h = relu(x @ W_in + b) -> h_bf; also x_bf ----
        float (*inp)[NODE_IN] = (float (*)[NODE_IN])smem;
        int n0 = (b - EB) * 32;
        for (int i = t; i < 32 * NODE_IN; i += 256) {
            int r = i >> 5, c = i & 31;
            int n = min(n0 + r, N_NODES - 1);
            inp[r][c] = x[(size_t)n * NODE_IN + c];
        }
        __syncthreads();
        for (int i = t; i < 32 * 16; i += 256) {
            int r = i >> 4, c = i & 15;
            int n = n0 + r;
            if (n < N_NODES) x_bf[(size_t)n * 16 + c] = pack2bf(inp[r][2 * c], inp[r][2 * c + 1]);
        }
        int wave = t >> 6, lane = t & 63;
        int c0 = lane * 2, c1 = c0 + 1;
        const float2* W2 = (const float2*)W_in;
        float acc[8][2];
#pragma unroll
        for (int j = 0; j < 8; j++) { acc[j][0] = b_in[c0]; acc[j][1] = b_in[c1]; }
#pragma unroll 2
        for (int k4 = 0; k4 < NODE_IN / 4; k4++) {
            float4 v[8];
#pragma unroll
            for (int j = 0; j < 8; j++) v[j] = *(const float4*)&inp[wave * 8 + j][k4 * 4];
#pragma unroll
            for (int kk = 0; kk < 4; kk++) {
                float2 w = W2[(k4 * 4 + kk) * 64 + lane];
#pragma unroll
                for (int j = 0; j < 8; j++) {
                    float vv = (&v[j].x)[kk];
                    acc[j][0] += vv * w.x;
                    acc[j][1] += vv * w.y;
                }
            }
        }
#pragma unroll
        for (int j = 0; j < 8; j++) {
            int n = n0 + wave * 8 + j;
            if (n < N_NODES)
                h_bf[(size_t)n * 64 + lane] = pack2bf(fmaxf(acc[j][0], 0.f), fmaxf(acc[j][1], 0.f));
        }
    } else {
        // ---- weight pre-transpose into bf16 fragment order ----
        int g = (b - EB - NB32) * 256 + t;
        const float* Wm;
        int base, gg;
        if (g < 5120) {        // W_src layer 0/1, K=160: 2560 groups each
            int l = g / 2560;
            gg = g - l * 2560;
            Wm = Wsrc + (size_t)l * GAT_IN * EMB;
            base = l * 20480;
        } else if (g < 7168) { // W_out, K=128: 2048 groups
            gg = g - 5120;
            Wm = Wout;
            base = GWT_OUT;
        } else {               // W_g
            gg = g - 7168;
            Wm = Wg;
            base = GWT_G;
        }
        int lane = gg & 63, tmp = gg >> 6;
        int nt = tmp & 7, kc = tmp >> 3;
        int quad = lane >> 4, l16 = lane & 15;
        int col = nt * 16 + l16, k0 = kc * 32 + quad * 8;
        unsigned int u[4];
#pragma unroll
        for (int j = 0; j < 4; j++)
            u[j] = pack2bf(Wm[(size_t)(k0 + 2 * j) * EMB + col],
                           Wm[(size_t)(k0 + 2 * j + 1) * EMB + col]);
        *(uint4*)(gwt + base + (size_t)gg * 8) = make_uint4(u[0], u[1], u[2], u[3]);
    }
}

// ---------------------------------------------------------------------------
// hierarchical scan over 8 shards; scan3 emits per-shard bases
// ---------------------------------------------------------------------------
__global__ __launch_bounds__(256) void scan1_kernel(const int* __restrict__ cnt8,
                                                    int* __restrict__ bsum) {
    __shared__ int sm[256];
    int t = threadIdx.x;
    int i = blockIdx.x * 256 + t;
    int tot = 0;
    if (i < N_NODES) {
#pragma unroll
        for (int s = 0; s < 8; s++) tot += cnt8[s * N_NODES + i];
    }
    sm[t] = tot;
    __syncthreads();
#pragma unroll
    for (int d = 128; d >= 1; d >>= 1) {
        if (t < d) sm[t] += sm[t + d];
        __syncthreads();
    }
    if (t == 0) bsum[blockIdx.x] = sm[0];
}

// scan2 fused with the tiny prep work (mean finish + M matrix + loop_ae)
__global__ __launch_bounds__(256) void scan2_prep_kernel(const int* __restrict__ bsum,
                                                         int* __restrict__ bbase,
                                                         const float* __restrict__ W_edge,
                                                         const float* __restrict__ att_edge,
                                                         float* __restrict__ meta) {
    __shared__ int sm[256];
    int t = threadIdx.x;
    int v = (t < NBLK) ? bsum[t] : 0;
    sm[t] = v;
    __syncthreads();
#pragma unroll
    for (int d = 1; d < 256; d <<= 1) {
        int u = (t >= d) ? sm[t - d] : 0;
        __syncthreads();
        sm[t] += u;
        __syncthreads();
    }
    if (t < NBLK) bbase[t] = sm[t] - v;  // exclusive

    // ---- prep: finish mean; M[l][k][h]; loop_ae ----
    if (t < EDGE_IN) meta[t] = meta[t] * (1.0f / (float)N_EDGES);
    __syncthreads();
    if (t < 128) {
        int l = t >> 6, k = (t >> 2) & 15, h = t & 3;
        const float* w = W_edge + ((size_t)l * EDGE_IN + k) * EMB + h * 32;
        const float* a = att_edge + (size_t)l * EMB + h * 32;
        float acc = 0.f;
#pragma unroll
        for (int c = 0; c < 32; c++) acc += w[c] * a[c];
        meta[16 + (l * 16 + k) * 4 + h] = acc;
    }
    __syncthreads();
    if (t < 8) {
        int l = t >> 2, h = t & 3;
        float acc = 0.f;
#pragma unroll
        for (int k = 0; k < EDGE_IN; k++) acc += meta[k] * meta[16 + (l * 16 + k) * 4 + h];
        meta[144 + t] = acc;
    }
}

__global__ __launch_bounds__(256) void scan3_kernel(const int* __restrict__ bbase,
                                                    const int* __restrict__ cnt8,
                                                    int* __restrict__ off,
                                                    int* __restrict__ shard_base) {
    __shared__ int sm[256];
    int t = threadIdx.x;
    int i = blockIdx.x * 256 + t;
    int c[8] = {0, 0, 0, 0, 0, 0, 0, 0};
    int tot = 0;
    if (i < N_NODES) {
#pragma unroll
        for (int s = 0; s < 8; s++) {
            c[s] = cnt8[s * N_NODES + i];
            tot += c[s];
        }
    }
    sm[t] = tot;
    __syncthreads();
#pragma unroll
    for (int d = 1; d < 256; d <<= 1) {
        int u = (t >= d) ? sm[t - d] : 0;
        __syncthreads();
        sm[t] += u;
        __syncthreads();
    }
    if (i < N_NODES) {
        int base = bbase[blockIdx.x] + sm[t] - tot;  // exclusive
        off[i] = base;
        int4 sb0, sb1;
        sb0.x = base;           base += c[0];
        sb0.y = base;           base += c[1];
        sb0.z = base;           base += c[2];
        sb0.w = base;           base += c[3];
        sb1.x = base;           base += c[4];
        sb1.y = base;           base += c[5];
        sb1.z = base;           base += c[6];
        sb1.w = base;
        *(int4*)(shard_base + (size_t)i * 8) = sb0;
        *(int4*)(shard_base + (size_t)i * 8 + 4) = sb1;
        if (i == N_NODES - 1) off[N_NODES] = E2;
    }
}

// ---------------------------------------------------------------------------
// fill_perm: minimal 8B scatter {src, e} -> pos (atomic-free).
// ---------------------------------------------------------------------------
__global__ __launch_bounds__(256) void fill_perm_kernel(const int* __restrict__ edge_index,
                                                        const int* __restrict__ rank,
                                                        const int* __restrict__ shard_base,
                                                        int* __restrict__ perm) {
    int e = blockIdx.x * 256 + threadIdx.x;
    if (e >= E2) return;
    int src, dst;
    if (e < N_EDGES) {
        src = edge_index[e];
        dst = edge_index[N_EDGES + e];
    } else {
        src = dst = e - N_EDGES;
    }
    int shard = (e >> 8) & 7;  // matches mega's blockIdx&7
    int pos = shard_base[(size_t)dst * 8 + shard] + rank[e];
    ((int2*)perm)[pos] = make_int2(src, e);
}

// ---------------------------------------------------------------------------
// compute_ae: stream positions in order; gather edge_attr[e] (one full 64B
// line per edge); write csr_src + csr_ae coalesced.
// ---------------------------------------------------------------------------
__global__ __launch_bounds__(256) void compute_ae_kernel(const int* __restrict__ perm,
                                                         const float* __restrict__ edge_attr,
                                                         const float* __restrict__ meta,
                                                         int* __restrict__ csr_src,
                                                         float* __restrict__ csr_ae0,
                                                         float* __restrict__ csr_ae1) {
    __shared__ float Ml[128];
    __shared__ float loop_ae[8];
    int t = threadIdx.x;
    if (t < 128) Ml[t] = meta[16 + t];
    if (t < 8) loop_ae[t] = meta[144 + t];
    __syncthreads();
    int p = blockIdx.x * 256 + t;
    if (p >= E2) return;
    int2 pe = ((const int2*)perm)[p];
    int src = pe.x, e = pe.y;
    csr_src[p] = src;
    float ae[2][4];
    if (e < N_EDGES) {
        const float4* r4 = (const float4*)(edge_attr + (size_t)e * EDGE_IN);
#pragma unroll
        for (int l = 0; l < 2; l++)
#pragma unroll
            for (int hh = 0; hh < 4; hh++) ae[l][hh] = 0.f;
#pragma unroll
        for (int q = 0; q < 4; q++) {
            float4 v = r4[q];
#pragma unroll
            for (int l = 0; l < 2; l++) {
                const float* M = Ml + l * 64;
#pragma unroll
                for (int hh = 0; hh < 4; hh++) {
                    ae[l][hh] += v.x * M[(4 * q + 0) * 4 + hh] + v.y * M[(4 * q + 1) * 4 + hh] +
                                 v.z * M[(4 * q + 2) * 4 + hh] + v.w * M[(4 * q + 3) * 4 + hh];
                }
            }
        }
    } else {
#pragma unroll
        for (int l = 0; l < 2; l++)
#pragma unroll
            for (int hh = 0; hh < 4; hh++) ae[l][hh] = loop_ae[l * 4 + hh];
    }
    *(float4*)(csr_ae0 + (size_t)p * 4) = make_float4(ae[0][0], ae[0][1], ae[0][2], ae[0][3]);
    *(float4*)(csr_ae1 + (size_t)p * 4) = make_float4(ae[1][0], ae[1][1], ae[1][2], ae[1][3]);
}

// ---------------------------------------------------------------------------
// MFMA dense kernel: C[64 nodes][128] = A @ W. A from bf16-packed global
// (x_bf/h_bf), B from pre-transposed fragment-ordered gwt (global, L2-hot).
// ---------------------------------------------------------------------------
template <int K, int MODE>
__global__ __launch_bounds__(256) void dense_mfma_kernel(
    const unsigned int* __restrict__ xbf, const unsigned int* __restrict__ hbf,
    const unsigned short* __restrict__ gwt, const float* __restrict__ bias,
    const float* __restrict__ v1, const float* __restrict__ v2,
    const int* __restrict__ batch,
    unsigned int* __restrict__ xs_out, float* __restrict__ a_s, float* __restrict__ a_d,
    float* __restrict__ out_nodes, float* __restrict__ gsum, float* __restrict__ gcnt) {
    constexpr int CLS = 132;
    __shared__ __align__(16) float cl[64 * CLS];            // 33 KB
    __shared__ float red[(MODE != 0) ? 64 : 1][8];
    __shared__ float locw[(MODE == 2) ? 4 : 1][2][EMB];
    __shared__ int bids[(MODE == 2) ? 64 : 1];

    int t = threadIdx.x;
    int n0 = blockIdx.x * 64;
    if (MODE == 2 && t < 64) bids[t] = batch[min(n0 + t, N_NODES - 1)];

    int wave = t >> 6, lane = t & 63;
    int quad = lane >> 4, l16 = lane & 15;
    int arow = min(n0 + wave * 16 + l16, N_NODES - 1);
    const bf16x8* B = (const bf16x8*)gwt;
    f32x4 acc[8];
#pragma unroll
    for (int i = 0; i < 8; i++) acc[i] = (f32x4){0.f, 0.f, 0.f, 0.f};
#pragma unroll
    for (int kc = 0; kc < K / 32; kc++) {
        bf16x8 af;
        if (MODE == 0 && kc == 0) {
            af = *(const bf16x8*)(xbf + (size_t)arow * 16 + quad * 4);
        } else {
            int hk = ((MODE == 0) ? (kc - 1) : kc) * 16;  // UINT units (32 bf16/chunk)
            af = *(const bf16x8*)(hbf + (size_t)arow * 64 + hk + quad * 4);
        }
#pragma unroll
        for (int nt = 0; nt < 8; nt++) {
            bf16x8 bfv = B[(kc * 8 + nt) * 64 + lane];
            acc[nt] = __builtin_amdgcn_mfma_f32_16x16x32_bf16(af, bfv, acc[nt], 0, 0, 0);
        }
    }
#pragma unroll
    for (int nt = 0; nt < 8; nt++) {
#pragma unroll
        for (int i = 0; i < 4; i++) {
            int r = wave * 16 + quad * 4 + i;  // C: row = quad*4+reg, col = l16
            cl[r * CLS + nt * 16 + l16] = acc[nt][i];
        }
    }
    __syncthreads();

    // row-wise epilogue: thread t -> node r = t>>2, part p = t&3 (32 cols)
    int p = t & 3, r = t >> 2;
    int n = n0 + r;
    const float4* c4 = (const float4*)(cl + r * CLS + p * 32);

    if (MODE == 0) {
        const float4* s4 = (const float4*)(v1 + p * 32);
        const float4* d4 = (const float4*)(v2 + p * 32);
        if (n < N_NODES) {
            float s_ = 0.f, d_ = 0.f;
#pragma unroll
            for (int i = 0; i < 8; i++) {
                float4 cv = c4[i], sv = s4[i], dv = d4[i];
                s_ += cv.x * sv.x + cv.y * sv.y + cv.z * sv.z + cv.w * sv.w;
                d_ += cv.x * dv.x + cv.y * dv.y + cv.z * dv.z + cv.w * dv.w;
                uint2 pk = make_uint2(pack2bf(cv.x, cv.y), pack2bf(cv.z, cv.w));
                *(uint2*)(xs_out + (size_t)n * 64 + p * 16 + 2 * i) = pk;
            }
            a_s[(size_t)n * 4 + p] = s_;
            a_d[(size_t)n * 4 + p] = d_;
        }
    } else {
        const float4* b4 = (const float4*)(bias + p * 32);
        float vals[32];
        float s_ = 0.f, q_ = 0.f;
#pragma unroll
        for (int i = 0; i < 8; i++) {
            float4 cv = c4[i], bv = b4[i];
            float w0 = fmaxf(cv.x + bv.x, 0.f), w1 = fmaxf(cv.y + bv.y, 0.f);
            float w2 = fmaxf(cv.z + bv.z, 0.f), w3 = fmaxf(cv.w + bv.w, 0.f);
            vals[4 * i] = w0; vals[4 * i + 1] = w1; vals[4 * i + 2] = w2; vals[4 * i + 3] = w3;
            s_ += w0 + w1 + w2 + w3;
            q_ += w0 * w0 + w1 * w1 + w2 * w2 + w3 * w3;
        }
        red[r][p] = s_;
        red[r][4 + p] = q_;
        __syncthreads();
        float sm = red[r][0] + red[r][1] + red[r][2] + red[r][3];
        float sq = red[r][4] + red[r][5] + red[r][6] + red[r][7];
        float mean = sm * (1.f / EMB);
        float var = sq * (1.f / EMB) - mean * mean;
        float rstd = rsqrtf(var + 1e-5f);
        const float4* g4 = (const float4*)(v1 + p * 32);
        const float4* be4 = (const float4*)(v2 + p * 32);
#pragma unroll
        for (int i = 0; i < 8; i++) {
            float4 gv = g4[i], bv = be4[i];
            vals[4 * i]     = (vals[4 * i]     - mean) * rstd * gv.x + bv.x;
            vals[4 * i + 1] = (vals[4 * i + 1] - mean) * rstd * gv.y + bv.y;
            vals[4 * i + 2] = (vals[4 * i + 2] - mean) * rstd * gv.z + bv.z;
            vals[4 * i + 3] = (vals[4 * i + 3] - mean) * rstd * gv.w + bv.w;
        }
        if (MODE == 1) {
            if (n < N_NODES) {
                float* op = out_nodes + (size_t)n * EMB + p * 32;
#pragma unroll
                for (int i = 0; i < 8; i++)
                    *(float4*)(op + 4 * i) = make_float4(vals[4 * i], vals[4 * i + 1],
                                                         vals[4 * i + 2], vals[4 * i + 3]);
            }
        } else {
            int nvalid = min(64, N_NODES - n0);
            int bmin = bids[0], bmax = bids[nvalid - 1];
            int bid = bids[r];
            bool inA = (bid == bmin) && (n < N_NODES);
            bool inB = (bid == bmax) && (bmax != bmin) && (n < N_NODES);
            if (n < N_NODES && bid != bmin && bid != bmax) {
#pragma unroll
                for (int i = 0; i < 32; i++)
                    atomicAdd(&gsum[(size_t)bid * EMB + p * 32 + i], vals[i]);
            }
#pragma unroll
            for (int g = 0; g < 2; g++) {
                bool m = g ? inB : inA;
#pragma unroll
                for (int i = 0; i < 32; i++) {
                    float v = m ? vals[i] : 0.f;
                    v += __shfl_xor(v, 4, 64);
                    v += __shfl_xor(v, 8, 64);
                    v += __shfl_xor(v, 16, 64);
                    v += __shfl_xor(v, 32, 64);
                    if ((lane >> 2) == 0) locw[wave][g][(lane & 3) * 32 + i] = v;
                }
            }
            __syncthreads();
            if (t < 128) {
                float sA = locw[0][0][t] + locw[1][0][t] + locw[2][0][t] + locw[3][0][t];
                atomicAdd(&gsum[(size_t)bmin * EMB + t], sA);
                if (bmax != bmin) {
                    float sB = locw[0][1][t] + locw[1][1][t] + locw[2][1][t] + locw[3][1][t];
                    atomicAdd(&gsum[(size_t)bmax * EMB + t], sB);
                }
            } else if (t == 255) {
                int cA = 0, cB = 0;
                for (int rr = 0; rr < nvalid; rr++) {
                    int bb = bids[rr];
                    if (bb == bmin) cA++;
                    else if (bb == bmax) cB++;
                    else atomicAdd(&gcnt[bb], 1.f);
                }
                atomicAdd(&gcnt[bmin], (float)cA);
                if (bmax != bmin && cB > 0) atomicAdd(&gcnt[bmax], (float)cB);
            }
        }
    }
}

// ---------------------------------------------------------------------------
// gather: wave per node; 16 lanes per edge, 4 edge-groups, 2-deep unroll
// (8 edges in flight). Each lane loads a uint4 (8 bf16 cols) of xs[src].
// Cross-group combine via shfl_xor(16/32); fused /denom + bias + LN + ELU.
// ---------------------------------------------------------------------------
__global__ __launch_bounds__(256) void gat_gather_kernel(const int* __restrict__ off,
                                                         const int* __restrict__ csr_src,
                                                         const float* __restrict__ csr_ae,
                                                         const unsigned int* __restrict__ xs,
                                                         const float* __restrict__ a_s,
                                                         const float* __restrict__ a_d,
                                                         const float* __restrict__ bias_l,
                                                         const float* __restrict__ gamma_l,
                                                         const float* __restrict__ beta_l,
                                                         unsigned int* __restrict__ h_bf) {
    int t = threadIdx.x, wave = t >> 6, lane = t & 63;
    int n = blockIdx.x * 4 + wave;  // grid = N/4 exactly
    int g = lane >> 4, l16 = lane & 15;
    int h = l16 >> 2;               // head for cols [l16*8, l16*8+8)
    float ad = a_d[(size_t)n * 4 + h];
    int p0 = __builtin_amdgcn_readfirstlane(off[n]);
    int p1 = __builtin_amdgcn_readfirstlane(off[n + 1]);
    int plast = p1 - 1;             // deg >= 1 always (self loop)
    float den = 0.f;
    float acc[8];
#pragma unroll
    for (int j = 0; j < 8; j++) acc[j] = 0.f;

    for (int pb = p0; pb < p1; pb += 8) {
        int pA = pb + g, pB = pb + 4 + g;
        int iA = min(pA, plast), iB = min(pB, plast);
        int sA = csr_src[iA], sB = csr_src[iB];
        float aeA = csr_ae[(size_t)iA * 4 + h];
        float aeB = csr_ae[(size_t)iB * 4 + h];
        float asA = a_s[(size_t)sA * 4 + h];
        float asB = a_s[(size_t)sB * 4 + h];
        uint4 xA = *(const uint4*)(xs + (size_t)sA * 64 + l16 * 4);
        uint4 xB = *(const uint4*)(xs + (size_t)sB * 64 + l16 * 4);
        float alA = asA + ad + aeA;
        alA = alA > 0.f ? alA : 0.2f * alA;
        float exA = (pA <= plast) ? __expf(alA) : 0.f;
        float alB = asB + ad + aeB;
        alB = alB > 0.f ? alB : 0.2f * alB;
        float exB = (pB <= plast) ? __expf(alB) : 0.f;
        den += exA + exB;
        unsigned int u;
        u = xA.x; acc[0] += exA * bf2f(u & 0xFFFFu); acc[1] += exA * bf2f(u >> 16);
        u = xA.y; acc[2] += exA * bf2f(u & 0xFFFFu); acc[3] += exA * bf2f(u >> 16);
        u = xA.z; acc[4] += exA * bf2f(u & 0xFFFFu); acc[5] += exA * bf2f(u >> 16);
        u = xA.w; acc[6] += exA * bf2f(u & 0xFFFFu); acc[7] += exA * bf2f(u >> 16);
        u = xB.x; acc[0] += exB * bf2f(u & 0xFFFFu); acc[1] += exB * bf2f(u >> 16);
        u = xB.y; acc[2] += exB * bf2f(u & 0xFFFFu); acc[3] += exB * bf2f(u >> 16);
        u = xB.z; acc[4] += exB * bf2f(u & 0xFFFFu); acc[5] += exB * bf2f(u >> 16);
        u = xB.w; acc[6] += exB * bf2f(u & 0xFFFFu); acc[7] += exB * bf2f(u >> 16);
    }
    // combine the 4 edge-groups (cols identical across groups)
#pragma unroll
    for (int j = 0; j < 8; j++) {
        acc[j] += __shfl_xor(acc[j], 16, 64);
        acc[j] += __shfl_xor(acc[j], 32, 64);
    }
    den += __shfl_xor(den, 16, 64);
    den += __shfl_xor(den, 32, 64);

    float dinv = 1.0f / (den + 1e-16f);
    int c0 = l16 * 8;
    const float4* b4 = (const float4*)(bias_l + c0);
    float4 bv0 = b4[0], bv1 = b4[1];
    float v[8];
    v[0] = acc[0] * dinv + bv0.x; v[1] = acc[1] * dinv + bv0.y;
    v[2] = acc[2] * dinv + bv0.z; v[3] = acc[3] * dinv + bv0.w;
    v[4] = acc[4] * dinv + bv1.x; v[5] = acc[5] * dinv + bv1.y;
    v[6] = acc[6] * dinv + bv1.z; v[7] = acc[7] * dinv + bv1.w;
    float sm = 0.f, sq = 0.f;
#pragma unroll
    for (int j = 0; j < 8; j++) { sm += v[j]; sq += v[j] * v[j]; }
#pragma unroll
    for (int o = 1; o <= 8; o <<= 1) {
        sm += __shfl_xor(sm, o, 64);
        sq += __shfl_xor(sq, o, 64);
    }
    float mean = sm * (1.f / EMB);
    float var = sq * (1.f / EMB) - mean * mean;
    float rstd = rsqrtf(var + 1e-5f);
    const float4* g4 = (const float4*)(gamma_l + c0);
    const float4* be4 = (const float4*)(beta_l + c0);
    float4 gv0 = g4[0], gv1 = g4[1], bev0 = be4[0], bev1 = be4[1];
    float y[8];
    y[0] = (v[0] - mean) * rstd * gv0.x + bev0.x;
    y[1] = (v[1] - mean) * rstd * gv0.y + bev0.y;
    y[2] = (v[2] - mean) * rstd * gv0.z + bev0.z;
    y[3] = (v[3] - mean) * rstd * gv0.w + bev0.w;
    y[4] = (v[4] - mean) * rstd * gv1.x + bev1.x;
    y[5] = (v[5] - mean) * rstd * gv1.y + bev1.y;
    y[6] = (v[6] - mean) * rstd * gv1.z + bev1.z;
    y[7] = (v[7] - mean) * rstd * gv1.w + bev1.w;
#pragma unroll
    for (int j = 0; j < 8; j++) y[j] = y[j] > 0.f ? y[j] : __expf(y[j]) - 1.f;  // elu
    if (g == 0) {
        uint4 o4;
        o4.x = pack2bf(y[0], y[1]);
        o4.y = pack2bf(y[2], y[3]);
        o4.z = pack2bf(y[4], y[5]);
        o4.w = pack2bf(y[6], y[7]);
        *(uint4*)(h_bf + (size_t)n * 64 + l16 * 4) = o4;
    }
}

__global__ void graph_out_kernel(const float* __restrict__ gsum, const float* __restrict__ gcnt,
                                 float* __restrict__ out) {
    int i = blockIdx.x * blockDim.x + threadIdx.x;
    if (i >= NGRAPH * EMB) return;
    int b = i >> 7;
    float c = fmaxf(gcnt[b], 1.f);
    out[(size_t)N_NODES * EMB + i] = gsum[i] / c;
}

// ---------------------------------------------------------------------------
extern "C" void kernel_launch(void* const* d_in, const int* in_sizes, int n_in,
                              void* d_out, int out_size, void* d_ws, size_t ws_size,
                              hipStream_t stream) {
    (void)in_sizes; (void)n_in; (void)out_size; (void)ws_size;
    const float* x         = (const float*)d_in[0];
    const float* edge_attr = (const float*)d_in[1];
    const float* W_in      = (const float*)d_in[2];
    const float* b_in      = (const float*)d_in[3];
    const float* W_src     = (const float*)d_in[4];
    const float* W_edge    = (const float*)d_in[5];
    const float* att_src   = (const float*)d_in[6];
    const float* att_dst   = (const float*)d_in[7];
    const float* att_edge  = (const float*)d_in[8];
    const float* gat_bias  = (const float*)d_in[9];
    const float* ln_gamma  = (const float*)d_in[10];
    const float* ln_beta   = (const float*)d_in[11];
    const float* W_out     = (const float*)d_in[12];
    const float* b_out     = (const float*)d_in[13];
    const float* ln_og     = (const float*)d_in[14];
    const float* ln_ob     = (const float*)d_in[15];
    const float* W_g       = (const float*)d_in[16];
    const float* b_g       = (const float*)d_in[17];
    const float* g_gamma   = (const float*)d_in[18];
    const float* g_beta    = (const float*)d_in[19];
    const int* edge_index  = (const int*)d_in[20];
    const int* batch       = (const int*)d_in[21];
    float* out = (float*)d_out;

    float* ws              = (float*)d_ws;
    unsigned int* h_bf     = (unsigned int*)ws;               // N*64
    unsigned int* xs       = h_bf + (size_t)N_NODES * 64;     // N*64
    unsigned int* x_bf     = xs + (size_t)N_NODES * 64;       // N*16
    float* a_s             = (float*)(x_bf + (size_t)N_NODES * 16);  // N*4
    float* a_d             = a_s + (size_t)N_NODES * 4;       // N*4
    float* csr_ae          = a_d + (size_t)N_NODES * 4;       // 2*E2*4
    unsigned short* gwt    = (unsigned short*)(csr_ae + (size_t)2 * E2 * 4);  // 73728 shorts
    float* meta            = (float*)(gwt + GWT_TOT);         // 152
    float* gsum            = meta + 152;                      // 1024
    float* gcnt            = gsum + NGRAPH * EMB;             // 8
    int*   cnt8            = (int*)(gcnt + NGRAPH);           // 8*N
    int*   off             = cnt8 + 8 * N_NODES;              // N+1
    int*   shard_base      = off + N_NODES + 1;               // 8*N
    int*   rank            = shard_base + 8 * N_NODES;        // E2
    int*   csr_src         = rank + E2;                       // E2
    int*   bsum            = csr_src + E2;                    // NBLK
    int*   bbase           = bsum + NBLK;                     // NBLK
    // perm (int2[E2] = 6.8MB) aliases xs: xs is first written by dense layer 0,
    // which runs after compute_ae has consumed perm. 16B-aligned.
    int*   perm            = (int*)xs;
    // total ~17M words = 68 MB (< 75.8 proven in round 8)

    zero_kernel<<<256, 256, 0, stream>>>(meta, 152 + NGRAPH * EMB + NGRAPH + 8 * N_NODES);
    mega_kernel<<<EB + NB32 + 36, 256, 0, stream>>>(
        edge_index, edge_attr, x, W_in, b_in, W_src, W_out, W_g,
        cnt8, rank, meta, h_bf, x_bf, gwt);

    scan1_kernel<<<NBLK, 256, 0, stream>>>(cnt8, bsum);
    scan2_prep_kernel<<<1, 256, 0, stream>>>(bsum, bbase, W_edge, att_edge, meta);
    scan3_kernel<<<NBLK, 256, 0, stream>>>(bbase, cnt8, off, shard_base);
    fill_perm_kernel<<<EB, 256, 0, stream>>>(edge_index, rank, shard_base, perm);
    compute_ae_kernel<<<EB, 256, 0, stream>>>(perm, edge_attr, meta,
                                              csr_src, csr_ae, csr_ae + (size_t)E2 * 4);

    for (int l = 0; l < NLAYER; l++) {
        dense_mfma_kernel<GAT_IN, 0><<<NB64, 256, 0, stream>>>(
            x_bf, h_bf, gwt + (l ? GWT_SRC1 : GWT_SRC0), nullptr,
            att_src + (size_t)l * EMB, att_dst + (size_t)l * EMB, nullptr,
            xs, a_s, a_d, nullptr, nullptr, nullptr);
        gat_gather_kernel<<<N_NODES / 4, 256, 0, stream>>>(
            off, csr_src, csr_ae + (size_t)l * E2 * 4, xs, a_s, a_d,
            gat_bias + (size_t)l * EMB, ln_gamma + (size_t)l * EMB,
            ln_beta + (size_t)l * EMB, h_bf);
    }

    dense_mfma_kernel<EMB, 1><<<NB64, 256, 0, stream>>>(
        nullptr, h_bf, gwt + GWT_OUT, b_out, ln_og, ln_ob, nullptr,
        nullptr, nullptr, nullptr, out, nullptr, nullptr);
    dense_mfma_kernel<EMB, 2><<<NB64, 256, 0, stream>>>(
        nullptr, h_bf, gwt + GWT_G, b_g, g_gamma, g_beta, batch,
        nullptr, nullptr, nullptr, nullptr, gsum, gcnt);
    graph_out_kernel<<<4, 256, 0, stream>>>(gsum, gcnt, out);
}

// Round 4
// 399.072 us; speedup vs baseline: 1.1778x; 1.0570x over previous
//
#include <hip/hip_runtime.h>

#define N_NODES 50000
#define N_EDGES 800000
#define E2      850000        // N_EDGES + N_NODES (self loops)
#define NODE_IN 32
#define EDGE_IN 16
#define EMB     128
#define GAT_IN  160           // NODE_IN + EMB
#define NLAYER  2
#define NGRAPH  8
#define NB32    1563          // ceil(N_NODES/32)
#define NB64    782           // ceil(N_NODES/64) for MFMA dense kernels
#define EB      3321          // ceil(E2/256)

// counting-sort geometry: bucket = dst>>9 (512 dsts/bucket), chunk = 4096 edges
#define NBUCK   98            // ceil(50000/512)
#define CHUNK   4096
#define NCHUNK  208           // ceil(E2/CHUNK)

// gwt (fragment-ordered bf16 W^T) offsets in shorts
#define GWT_SRC0 0
#define GWT_SRC1 20480
#define GWT_OUT  40960
#define GWT_G    57344
#define GWT_TOT  73728

typedef short bf16x8 __attribute__((ext_vector_type(8)));
typedef float f32x4 __attribute__((ext_vector_type(4)));

// bf16 pack/unpack without hip_bf16.h (round-to-nearest-even)
__device__ __forceinline__ unsigned int f2bf(float f) {
    unsigned int u = __float_as_uint(f);
    return (u + 0x7FFFu + ((u >> 16) & 1u)) >> 16;
}
__device__ __forceinline__ float bf2f(unsigned int h) {
    return __uint_as_float(h << 16);
}
__device__ __forceinline__ unsigned int pack2bf(float a, float b) {
    return f2bf(a) | (f2bf(b) << 16);
}

// ---------------------------------------------------------------------------
__global__ void zero_kernel(float* __restrict__ p, int n) {
    int i = blockIdx.x * blockDim.x + threadIdx.x;
    int stride = gridDim.x * blockDim.x;
    for (; i < n; i += stride) p[i] = 0.f;
}

// ---------------------------------------------------------------------------
// mega kernel: four independent phases in one launch.
//   blocks [0, NCHUNK):        pass A — per-chunk LDS bucket histogram (no
//                              global atomics; bucket = dst>>9)
//   blocks [NCHUNK, +512):     edge_attr mean (streaming)
//   blocks [+512, +NB32):      input projection (x -> h_bf, x_bf)
//   blocks [+NB32, +36):       weight pre-transpose into gwt
// ---------------------------------------------------------------------------
__global__ __launch_bounds__(256) void mega_kernel(
    const int* __restrict__ edge_index, const float* __restrict__ edge_attr,
    const float* __restrict__ x, const float* __restrict__ W_in,
    const float* __restrict__ b_in,
    const float* __restrict__ Wsrc, const float* __restrict__ Wout,
    const float* __restrict__ Wg,
    int* __restrict__ hist, float* __restrict__ meta,
    unsigned int* __restrict__ h_bf, unsigned int* __restrict__ x_bf,
    unsigned short* __restrict__ gwt) {
    __shared__ float smem[32 * NODE_IN];  // 4 KB union
    int b = blockIdx.x, t = threadIdx.x;

    if (b < NCHUNK) {
        // ---- pass A: LDS histogram of dst>>9 for this 4096-edge chunk ----
        int* lh = (int*)smem;
        if (t < NBUCK) lh[t] = 0;
        __syncthreads();
        int c0 = b * CHUNK;
#pragma unroll
        for (int i = 0; i < CHUNK / 256; i++) {
            int e = c0 + i * 256 + t;
            if (e < E2) {
                int dst = (e < N_EDGES) ? edge_index[N_EDGES + e] : (e - N_EDGES);
                atomicAdd(&lh[dst >> 9], 1);
            }
        }
        __syncthreads();
        if (t < NBUCK) hist[t * NCHUNK + b] = lh[t];  // bucket-major
    } else if (b < NCHUNK + 512) {
        // ---- edge_attr mean ----
        if (t < 16) smem[t] = 0.f;
        __syncthreads();
        int gid = (b - NCHUNK) * 256 + t;
        int q = gid & 3;  // stride 512*256 divisible by 4 -> q constant
        const float4* ea4 = (const float4*)edge_attr;
        float4 s = make_float4(0.f, 0.f, 0.f, 0.f);
        for (int j = gid; j < N_EDGES * 4; j += 512 * 256) {
            float4 v = ea4[j];
            s.x += v.x; s.y += v.y; s.z += v.z; s.w += v.w;
        }
        atomicAdd(&smem[q * 4 + 0], s.x);
        atomicAdd(&smem[q * 4 + 1], s.y);
        atomicAdd(&smem[q * 4 + 2], s.z);
        atomicAdd(&smem[q * 4 + 3], s.w);
        __syncthreads();
        if (t < 16) atomicAdd(&meta[t], smem[t]);
    } else if (b < NCHUNK + 512 + NB32) {
        // ---- input projection: h = relu(x @ W_in + b) -> h_bf; also x_bf ----
        float (*inp)[NODE_IN] = (float (*)[NODE_IN])smem;
        int n0 = (b - NCHUNK - 512) * 32;
        for (int i = t; i < 32 * NODE_IN; i += 256) {
            int r = i >> 5, c = i & 31;
            int n = min(n0 + r, N_NODES - 1);
            inp[r][c] = x[(size_t)n * NODE_IN + c];
        }
        __syncthreads();
        for (int i = t; i < 32 * 16; i += 256) {
            int r = i >> 4, c = i & 15;
            int n = n0 + r;
            if (n < N_NODES) x_bf[(size_t)n * 16 + c] = pack2bf(inp[r][2 * c], inp[r][2 * c + 1]);
        }
        int wave = t >> 6, lane = t & 63;
        int c0 = lane * 2, c1 = c0 + 1;
        const float2* W2 = (const float2*)W_in;
        float acc[8][2];
#pragma unroll
        for (int j = 0; j < 8; j++) { acc[j][0] = b_in[c0]; acc[j][1] = b_in[c1]; }
#pragma unroll 2
        for (int k4 = 0; k4 < NODE_IN / 4; k4++) {
            float4 v[8];
#pragma unroll
            for (int j = 0; j < 8; j++) v[j] = *(const float4*)&inp[wave * 8 + j][k4 * 4];
#pragma unroll
            for (int kk = 0; kk < 4; kk++) {
                float2 w = W2[(k4 * 4 + kk) * 64 + lane];
#pragma unroll
                for (int j = 0; j < 8; j++) {
                    float vv = (&v[j].x)[kk];
                    acc[j][0] += vv * w.x;
                    acc[j][1] += vv * w.y;
                }
            }
        }
#pragma unroll
        for (int j = 0; j < 8; j++) {
            int n = n0 + wave * 8 + j;
            if (n < N_NODES)
                h_bf[(size_t)n * 64 + lane] = pack2bf(fmaxf(acc[j][0], 0.f), fmaxf(acc[j][1], 0.f));
        }
    } else {
        // ---- weight pre-transpose into bf16 fragment order ----
        int g = (b - NCHUNK - 512 - NB32) * 256 + t;
        const float* Wm;
        int base, gg;
        if (g < 5120) {        // W_src layer 0/1, K=160: 2560 groups each
            int l = g / 2560;
            gg = g - l * 2560;
            Wm = Wsrc + (size_t)l * GAT_IN * EMB;
            base = l * 20480;
        } else if (g < 7168) { // W_out, K=128: 2048 groups
            gg = g - 5120;
            Wm = Wout;
            base = GWT_OUT;
        } else {               // W_g
            gg = g - 7168;
            Wm = Wg;
            base = GWT_G;
        }
        int lane = gg & 63, tmp = gg >> 6;
        int nt = tmp & 7, kc = tmp >> 3;
        int quad = lane >> 4, l16 = lane & 15;
        int col = nt * 16 + l16, k0 = kc * 32 + quad * 8;
        unsigned int u[4];
#pragma unroll
        for (int j = 0; j < 4; j++)
            u[j] = pack2bf(Wm[(size_t)(k0 + 2 * j) * EMB + col],
                           Wm[(size_t)(k0 + 2 * j + 1) * EMB + col]);
        *(uint4*)(gwt + base + (size_t)gg * 8) = make_uint4(u[0], u[1], u[2], u[3]);
    }
}

// ---------------------------------------------------------------------------
// bucket_scan: per-bucket exclusive scan over the 208 chunk counts (in place)
// + bucket totals. grid = NBUCK.
// ---------------------------------------------------------------------------
__global__ __launch_bounds__(256) void bucket_scan_kernel(int* __restrict__ hist,
                                                          int* __restrict__ btot) {
    __shared__ int sm[256];
    int k = blockIdx.x, t = threadIdx.x;
    int v = (t < NCHUNK) ? hist[k * NCHUNK + t] : 0;
    sm[t] = v;
    __syncthreads();
#pragma unroll
    for (int d = 1; d < 256; d <<= 1) {
        int u = (t >= d) ? sm[t - d] : 0;
        __syncthreads();
        sm[t] += u;
        __syncthreads();
    }
    if (t < NCHUNK) hist[k * NCHUNK + t] = sm[t] - v;  // exclusive
    if (t == 255) btot[k] = sm[255];
}

// ---------------------------------------------------------------------------
// base_prep: scan bucket totals -> bucket_base; plus tiny prep math
// (mean finish + M matrix + loop_ae). 1 block.
// ---------------------------------------------------------------------------
__global__ __launch_bounds__(256) void base_prep_kernel(const int* __restrict__ btot,
                                                        int* __restrict__ bucket_base,
                                                        const float* __restrict__ W_edge,
                                                        const float* __restrict__ att_edge,
                                                        float* __restrict__ meta) {
    __shared__ int sm[256];
    int t = threadIdx.x;
    int v = (t < NBUCK) ? btot[t] : 0;
    sm[t] = v;
    __syncthreads();
#pragma unroll
    for (int d = 1; d < 256; d <<= 1) {
        int u = (t >= d) ? sm[t - d] : 0;
        __syncthreads();
        sm[t] += u;
        __syncthreads();
    }
    if (t < NBUCK) bucket_base[t] = sm[t] - v;  // exclusive
    if (t == NBUCK - 1) bucket_base[NBUCK] = sm[t];  // == E2

    // ---- prep: finish mean; M[l][k][h]; loop_ae ----
    if (t < EDGE_IN) meta[t] = meta[t] * (1.0f / (float)N_EDGES);
    __syncthreads();
    if (t < 128) {
        int l = t >> 6, k = (t >> 2) & 15, h = t & 3;
        const float* w = W_edge + ((size_t)l * EDGE_IN + k) * EMB + h * 32;
        const float* a = att_edge + (size_t)l * EMB + h * 32;
        float acc = 0.f;
#pragma unroll
        for (int c = 0; c < 32; c++) acc += w[c] * a[c];
        meta[16 + (l * 16 + k) * 4 + h] = acc;
    }
    __syncthreads();
    if (t < 8) {
        int l = t >> 2, h = t & 3;
        float acc = 0.f;
#pragma unroll
        for (int k = 0; k < EDGE_IN; k++) acc += meta[k] * meta[16 + (l * 16 + k) * 4 + h];
        meta[144 + t] = acc;
    }
}

// ---------------------------------------------------------------------------
// scatter_bucket (pass B): re-read chunk edges, scatter {src|dstlow<<16, e}
// into pre-reserved disjoint bucket ranges via LDS cursors. No global atomics.
// ---------------------------------------------------------------------------
__global__ __launch_bounds__(256) void scatter_bucket_kernel(const int* __restrict__ edge_index,
                                                             const int* __restrict__ hist,
                                                             const int* __restrict__ bucket_base,
                                                             int2* __restrict__ brec) {
    __shared__ int cur[NBUCK];
    int b = blockIdx.x, t = threadIdx.x;
    if (t < NBUCK) cur[t] = bucket_base[t] + hist[t * NCHUNK + b];
    __syncthreads();
    int c0 = b * CHUNK;
#pragma unroll
    for (int i = 0; i < CHUNK / 256; i++) {
        int e = c0 + i * 256 + t;
        if (e < E2) {
            int src, dst;
            if (e < N_EDGES) {
                src = edge_index[e];
                dst = edge_index[N_EDGES + e];
            } else {
                src = dst = e - N_EDGES;
            }
            int pos = atomicAdd(&cur[dst >> 9], 1);
            brec[pos] = make_int2(src | ((dst & 511) << 16), e);
        }
    }
}

// ---------------------------------------------------------------------------
// local_sort (pass C): per bucket, LDS histogram + scan over dst&511, write
// off[] and scatter perm{src,e} in final CSR order. grid = NBUCK x 512.
// ---------------------------------------------------------------------------
__global__ __launch_bounds__(512) void local_sort_kernel(const int* __restrict__ bucket_base,
                                                         const int2* __restrict__ brec,
                                                         int* __restrict__ off,
                                                         int2* __restrict__ perm) {
    __shared__ int lh[512];
    __shared__ int sm[512];
    int k = blockIdx.x, t = threadIdx.x;
    int base = bucket_base[k], end = bucket_base[k + 1], cnt = end - base;
    lh[t] = 0;
    __syncthreads();
    for (int i = t; i < cnt; i += 512) {
        int2 r = brec[base + i];
        atomicAdd(&lh[(r.x >> 16) & 511], 1);
    }
    __syncthreads();
    int v = lh[t];
    sm[t] = v;
    __syncthreads();
#pragma unroll
    for (int d = 1; d < 512; d <<= 1) {
        int u = (t >= d) ? sm[t - d] : 0;
        __syncthreads();
        sm[t] += u;
        __syncthreads();
    }
    int excl = sm[t] - v;
    int dst = (k << 9) + t;
    if (dst < N_NODES) off[dst] = base + excl;
    if (k == NBUCK - 1 && t == 0) off[N_NODES] = E2;
    lh[t] = excl;  // cursor
    __syncthreads();
    for (int i = t; i < cnt; i += 512) {
        int2 r = brec[base + i];
        int dl = (r.x >> 16) & 511;
        int p = atomicAdd(&lh[dl], 1);
        perm[base + p] = make_int2(r.x & 0xFFFF, r.y);
    }
}

// ---------------------------------------------------------------------------
// compute_ae: stream positions in order; gather edge_attr[e] (one full 64B
// line per edge); write csr_src + csr_ae coalesced.
// ---------------------------------------------------------------------------
__global__ __launch_bounds__(256) void compute_ae_kernel(const int2* __restrict__ perm,
                                                         const float* __restrict__ edge_attr,
                                                         const float* __restrict__ meta,
                                                         int* __restrict__ csr_src,
                                                         float* __restrict__ csr_ae0,
                                                         float* __restrict__ csr_ae1) {
    __shared__ float Ml[128];
    __shared__ float loop_ae[8];
    int t = threadIdx.x;
    if (t < 128) Ml[t] = meta[16 + t];
    if (t < 8) loop_ae[t] = meta[144 + t];
    __syncthreads();
    int p = blockIdx.x * 256 + t;
    if (p >= E2) return;
    int2 pe = perm[p];
    int src = pe.x, e = pe.y;
    csr_src[p] = src;
    float ae[2][4];
    if (e < N_EDGES) {
        const float4* r4 = (const float4*)(edge_attr + (size_t)e * EDGE_IN);
#pragma unroll
        for (int l = 0; l < 2; l++)
#pragma unroll
            for (int hh = 0; hh < 4; hh++) ae[l][hh] = 0.f;
#pragma unroll
        for (int q = 0; q < 4; q++) {
            float4 v = r4[q];
#pragma unroll
            for (int l = 0; l < 2; l++) {
                const float* M = Ml + l * 64;
#pragma unroll
                for (int hh = 0; hh < 4; hh++) {
                    ae[l][hh] += v.x * M[(4 * q + 0) * 4 + hh] + v.y * M[(4 * q + 1) * 4 + hh] +
                                 v.z * M[(4 * q + 2) * 4 + hh] + v.w * M[(4 * q + 3) * 4 + hh];
                }
            }
        }
    } else {
#pragma unroll
        for (int l = 0; l < 2; l++)
#pragma unroll
            for (int hh = 0; hh < 4; hh++) ae[l][hh] = loop_ae[l * 4 + hh];
    }
    *(float4*)(csr_ae0 + (size_t)p * 4) = make_float4(ae[0][0], ae[0][1], ae[0][2], ae[0][3]);
    *(float4*)(csr_ae1 + (size_t)p * 4) = make_float4(ae[1][0], ae[1][1], ae[1][2], ae[1][3]);
}

// ---------------------------------------------------------------------------
// MFMA dense kernel: C[64 nodes][128] = A @ W. A from bf16-packed global
// (x_bf/h_bf), B from pre-transposed fragment-ordered gwt (global, L2-hot).
// ---------------------------------------------------------------------------
template <int K, int MODE>
__global__ __launch_bounds__(256) void dense_mfma_kernel(
    const unsigned int* __restrict__ xbf, const unsigned int* __restrict__ hbf,
    const unsigned short* __restrict__ gwt, const float* __restrict__ bias,
    const float* __restrict__ v1, const float* __restrict__ v2,
    const int* __restrict__ batch,
    unsigned int* __restrict__ xs_out, float* __restrict__ a_s, float* __restrict__ a_d,
    float* __restrict__ out_nodes, float* __restrict__ gsum, float* __restrict__ gcnt) {
    constexpr int CLS = 132;
    __shared__ __align__(16) float cl[64 * CLS];            // 33 KB
    __shared__ float red[(MODE != 0) ? 64 : 1][8];
    __shared__ float locw[(MODE == 2) ? 4 : 1][2][EMB];
    __shared__ int bids[(MODE == 2) ? 64 : 1];

    int t = threadIdx.x;
    int n0 = blockIdx.x * 64;
    if (MODE == 2 && t < 64) bids[t] = batch[min(n0 + t, N_NODES - 1)];

    int wave = t >> 6, lane = t & 63;
    int quad = lane >> 4, l16 = lane & 15;
    int arow = min(n0 + wave * 16 + l16, N_NODES - 1);
    const bf16x8* B = (const bf16x8*)gwt;
    f32x4 acc[8];
#pragma unroll
    for (int i = 0; i < 8; i++) acc[i] = (f32x4){0.f, 0.f, 0.f, 0.f};
#pragma unroll
    for (int kc = 0; kc < K / 32; kc++) {
        bf16x8 af;
        if (MODE == 0 && kc == 0) {
            af = *(const bf16x8*)(xbf + (size_t)arow * 16 + quad * 4);
        } else {
            int hk = ((MODE == 0) ? (kc - 1) : kc) * 16;  // UINT units (32 bf16/chunk)
            af = *(const bf16x8*)(hbf + (size_t)arow * 64 + hk + quad * 4);
        }
#pragma unroll
        for (int nt = 0; nt < 8; nt++) {
            bf16x8 bfv = B[(kc * 8 + nt) * 64 + lane];
            acc[nt] = __builtin_amdgcn_mfma_f32_16x16x32_bf16(af, bfv, acc[nt], 0, 0, 0);
        }
    }
#pragma unroll
    for (int nt = 0; nt < 8; nt++) {
#pragma unroll
        for (int i = 0; i < 4; i++) {
            int r = wave * 16 + quad * 4 + i;  // C: row = quad*4+reg, col = l16
            cl[r * CLS + nt * 16 + l16] = acc[nt][i];
        }
    }
    __syncthreads();

    // row-wise epilogue: thread t -> node r = t>>2, part p = t&3 (32 cols)
    int p = t & 3, r = t >> 2;
    int n = n0 + r;
    const float4* c4 = (const float4*)(cl + r * CLS + p * 32);

    if (MODE == 0) {
        const float4* s4 = (const float4*)(v1 + p * 32);
        const float4* d4 = (const float4*)(v2 + p * 32);
        if (n < N_NODES) {
            float s_ = 0.f, d_ = 0.f;
#pragma unroll
            for (int i = 0; i < 8; i++) {
                float4 cv = c4[i], sv = s4[i], dv = d4[i];
                s_ += cv.x * sv.x + cv.y * sv.y + cv.z * sv.z + cv.w * sv.w;
                d_ += cv.x * dv.x + cv.y * dv.y + cv.z * dv.z + cv.w * dv.w;
                uint2 pk = make_uint2(pack2bf(cv.x, cv.y), pack2bf(cv.z, cv.w));
                *(uint2*)(xs_out + (size_t)n * 64 + p * 16 + 2 * i) = pk;
            }
            a_s[(size_t)n * 4 + p] = s_;
            a_d[(size_t)n * 4 + p] = d_;
        }
    } else {
        const float4* b4 = (const float4*)(bias + p * 32);
        float vals[32];
        float s_ = 0.f, q_ = 0.f;
#pragma unroll
        for (int i = 0; i < 8; i++) {
            float4 cv = c4[i], bv = b4[i];
            float w0 = fmaxf(cv.x + bv.x, 0.f), w1 = fmaxf(cv.y + bv.y, 0.f);
            float w2 = fmaxf(cv.z + bv.z, 0.f), w3 = fmaxf(cv.w + bv.w, 0.f);
            vals[4 * i] = w0; vals[4 * i + 1] = w1; vals[4 * i + 2] = w2; vals[4 * i + 3] = w3;
            s_ += w0 + w1 + w2 + w3;
            q_ += w0 * w0 + w1 * w1 + w2 * w2 + w3 * w3;
        }
        red[r][p] = s_;
        red[r][4 + p] = q_;
        __syncthreads();
        float sm = red[r][0] + red[r][1] + red[r][2] + red[r][3];
        float sq = red[r][4] + red[r][5] + red[r][6] + red[r][7];
        float mean = sm * (1.f / EMB);
        float var = sq * (1.f / EMB) - mean * mean;
        float rstd = rsqrtf(var + 1e-5f);
        const float4* g4 = (const float4*)(v1 + p * 32);
        const float4* be4 = (const float4*)(v2 + p * 32);
#pragma unroll
        for (int i = 0; i < 8; i++) {
            float4 gv = g4[i], bv = be4[i];
            vals[4 * i]     = (vals[4 * i]     - mean) * rstd * gv.x + bv.x;
            vals[4 * i + 1] = (vals[4 * i + 1] - mean) * rstd * gv.y + bv.y;
            vals[4 * i + 2] = (vals[4 * i + 2] - mean) * rstd * gv.z + bv.z;
            vals[4 * i + 3] = (vals[4 * i + 3] - mean) * rstd * gv.w + bv.w;
        }
        if (MODE == 1) {
            if (n < N_NODES) {
                float* op = out_nodes + (size_t)n * EMB + p * 32;
#pragma unroll
                for (int i = 0; i < 8; i++)
                    *(float4*)(op + 4 * i) = make_float4(vals[4 * i], vals[4 * i + 1],
                                                         vals[4 * i + 2], vals[4 * i + 3]);
            }
        } else {
            int nvalid = min(64, N_NODES - n0);
            int bmin = bids[0], bmax = bids[nvalid - 1];
            int bid = bids[r];
            bool inA = (bid == bmin) && (n < N_NODES);
            bool inB = (bid == bmax) && (bmax != bmin) && (n < N_NODES);
            if (n < N_NODES && bid != bmin && bid != bmax) {
#pragma unroll
                for (int i = 0; i < 32; i++)
                    atomicAdd(&gsum[(size_t)bid * EMB + p * 32 + i], vals[i]);
            }
#pragma unroll
            for (int g = 0; g < 2; g++) {
                bool m = g ? inB : inA;
#pragma unroll
                for (int i = 0; i < 32; i++) {
                    float v = m ? vals[i] : 0.f;
                    v += __shfl_xor(v, 4, 64);
                    v += __shfl_xor(v, 8, 64);
                    v += __shfl_xor(v, 16, 64);
                    v += __shfl_xor(v, 32, 64);
                    if ((lane >> 2) == 0) locw[wave][g][(lane & 3) * 32 + i] = v;
                }
            }
            __syncthreads();
            if (t < 128) {
                float sA = locw[0][0][t] + locw[1][0][t] + locw[2][0][t] + locw[3][0][t];
                atomicAdd(&gsum[(size_t)bmin * EMB + t], sA);
                if (bmax != bmin) {
                    float sB = locw[0][1][t] + locw[1][1][t] + locw[2][1][t] + locw[3][1][t];
                    atomicAdd(&gsum[(size_t)bmax * EMB + t], sB);
                }
            } else if (t == 255) {
                int cA = 0, cB = 0;
                for (int rr = 0; rr < nvalid; rr++) {
                    int bb = bids[rr];
                    if (bb == bmin) cA++;
                    else if (bb == bmax) cB++;
                    else atomicAdd(&gcnt[bb], 1.f);
                }
                atomicAdd(&gcnt[bmin], (float)cA);
                if (bmax != bmin && cB > 0) atomicAdd(&gcnt[bmax], (float)cB);
            }
        }
    }
}

// ---------------------------------------------------------------------------
// gather: wave per node; 16 lanes per edge, 4 edge-groups, 2-deep unroll
// (8 edges in flight). Each lane loads a uint4 (8 bf16 cols) of xs[src].
// Cross-group combine via shfl_xor(16/32); fused /denom + bias + LN + ELU.
// ---------------------------------------------------------------------------
__global__ __launch_bounds__(256) void gat_gather_kernel(const int* __restrict__ off,
                                                         const int* __restrict__ csr_src,
                                                         const float* __restrict__ csr_ae,
                                                         const unsigned int* __restrict__ xs,
                                                         const float* __restrict__ a_s,
                                                         const float* __restrict__ a_d,
                                                         const float* __restrict__ bias_l,
                                                         const float* __restrict__ gamma_l,
                                                         const float* __restrict__ beta_l,
                                                         unsigned int* __restrict__ h_bf) {
    int t = threadIdx.x, wave = t >> 6, lane = t & 63;
    int n = blockIdx.x * 4 + wave;  // grid = N/4 exactly
    int g = lane >> 4, l16 = lane & 15;
    int h = l16 >> 2;               // head for cols [l16*8, l16*8+8)
    float ad = a_d[(size_t)n * 4 + h];
    int p0 = __builtin_amdgcn_readfirstlane(off[n]);
    int p1 = __builtin_amdgcn_readfirstlane(off[n + 1]);
    int plast = p1 - 1;             // deg >= 1 always (self loop)
    float den = 0.f;
    float acc[8];
#pragma unroll
    for (int j = 0; j < 8; j++) acc[j] = 0.f;

    for (int pb = p0; pb < p1; pb += 8) {
        int pA = pb + g, pB = pb + 4 + g;
        int iA = min(pA, plast), iB = min(pB, plast);
        int sA = csr_src[iA], sB = csr_src[iB];
        float aeA = csr_ae[(size_t)iA * 4 + h];
        float aeB = csr_ae[(size_t)iB * 4 + h];
        float asA = a_s[(size_t)sA * 4 + h];
        float asB = a_s[(size_t)sB * 4 + h];
        uint4 xA = *(const uint4*)(xs + (size_t)sA * 64 + l16 * 4);
        uint4 xB = *(const uint4*)(xs + (size_t)sB * 64 + l16 * 4);
        float alA = asA + ad + aeA;
        alA = alA > 0.f ? alA : 0.2f * alA;
        float exA = (pA <= plast) ? __expf(alA) : 0.f;
        float alB = asB + ad + aeB;
        alB = alB > 0.f ? alB : 0.2f * alB;
        float exB = (pB <= plast) ? __expf(alB) : 0.f;
        den += exA + exB;
        unsigned int u;
        u = xA.x; acc[0] += exA * bf2f(u & 0xFFFFu); acc[1] += exA * bf2f(u >> 16);
        u = xA.y; acc[2] += exA * bf2f(u & 0xFFFFu); acc[3] += exA * bf2f(u >> 16);
        u = xA.z; acc[4] += exA * bf2f(u & 0xFFFFu); acc[5] += exA * bf2f(u >> 16);
        u = xA.w; acc[6] += exA * bf2f(u & 0xFFFFu); acc[7] += exA * bf2f(u >> 16);
        u = xB.x; acc[0] += exB * bf2f(u & 0xFFFFu); acc[1] += exB * bf2f(u >> 16);
        u = xB.y; acc[2] += exB * bf2f(u & 0xFFFFu); acc[3] += exB * bf2f(u >> 16);
        u = xB.z; acc[4] += exB * bf2f(u & 0xFFFFu); acc[5] += exB * bf2f(u >> 16);
        u = xB.w; acc[6] += exB * bf2f(u & 0xFFFFu); acc[7] += exB * bf2f(u >> 16);
    }
    // combine the 4 edge-groups (cols identical across groups)
#pragma unroll
    for (int j = 0; j < 8; j++) {
        acc[j] += __shfl_xor(acc[j], 16, 64);
        acc[j] += __shfl_xor(acc[j], 32, 64);
    }
    den += __shfl_xor(den, 16, 64);
    den += __shfl_xor(den, 32, 64);

    float dinv = 1.0f / (den + 1e-16f);
    int c0 = l16 * 8;
    const float4* b4 = (const float4*)(bias_l + c0);
    float4 bv0 = b4[0], bv1 = b4[1];
    float v[8];
    v[0] = acc[0] * dinv + bv0.x; v[1] = acc[1] * dinv + bv0.y;
    v[2] = acc[2] * dinv + bv0.z; v[3] = acc[3] * dinv + bv0.w;
    v[4] = acc[4] * dinv + bv1.x; v[5] = acc[5] * dinv + bv1.y;
    v[6] = acc[6] * dinv + bv1.z; v[7] = acc[7] * dinv + bv1.w;
    float sm = 0.f, sq = 0.f;
#pragma unroll
    for (int j = 0; j < 8; j++) { sm += v[j]; sq += v[j] * v[j]; }
#pragma unroll
    for (int o = 1; o <= 8; o <<= 1) {
        sm += __shfl_xor(sm, o, 64);
        sq += __shfl_xor(sq, o, 64);
    }
    float mean = sm * (1.f / EMB);
    float var = sq * (1.f / EMB) - mean * mean;
    float rstd = rsqrtf(var + 1e-5f);
    const float4* g4 = (const float4*)(gamma_l + c0);
    const float4* be4 = (const float4*)(beta_l + c0);
    float4 gv0 = g4[0], gv1 = g4[1], bev0 = be4[0], bev1 = be4[1];
    float y[8];
    y[0] = (v[0] - mean) * rstd * gv0.x + bev0.x;
    y[1] = (v[1] - mean) * rstd * gv0.y + bev0.y;
    y[2] = (v[2] - mean) * rstd * gv0.z + bev0.z;
    y[3] = (v[3] - mean) * rstd * gv0.w + bev0.w;
    y[4] = (v[4] - mean) * rstd * gv1.x + bev1.x;
    y[5] = (v[5] - mean) * rstd * gv1.y + bev1.y;
    y[6] = (v[6] - mean) * rstd * gv1.z + bev1.z;
    y[7] = (v[7] - mean) * rstd * gv1.w + bev1.w;
#pragma unroll
    for (int j = 0; j < 8; j++) y[j] = y[j] > 0.f ? y[j] : __expf(y[j]) - 1.f;  // elu
    if (g == 0) {
        uint4 o4;
        o4.x = pack2bf(y[0], y[1]);
        o4.y = pack2bf(y[2], y[3]);
        o4.z = pack2bf(y[4], y[5]);
        o4.w = pack2bf(y[6], y[7]);
        *(uint4*)(h_bf + (size_t)n * 64 + l16 * 4) = o4;
    }
}

__global__ void graph_out_kernel(const float* __restrict__ gsum, const float* __restrict__ gcnt,
                                 float* __restrict__ out) {
    int i = blockIdx.x * blockDim.x + threadIdx.x;
    if (i >= NGRAPH * EMB) return;
    int b = i >> 7;
    float c = fmaxf(gcnt[b], 1.f);
    out[(size_t)N_NODES * EMB + i] = gsum[i] / c;
}

// ---------------------------------------------------------------------------
extern "C" void kernel_launch(void* const* d_in, const int* in_sizes, int n_in,
                              void* d_out, int out_size, void* d_ws, size_t ws_size,
                              hipStream_t stream) {
    (void)in_sizes; (void)n_in; (void)out_size; (void)ws_size;
    const float* x         = (const float*)d_in[0];
    const float* edge_attr = (const float*)d_in[1];
    const float* W_in      = (const float*)d_in[2];
    const float* b_in      = (const float*)d_in[3];
    const float* W_src     = (const float*)d_in[4];
    const float* W_edge    = (const float*)d_in[5];
    const float* att_src   = (const float*)d_in[6];
    const float* att_dst   = (const float*)d_in[7];
    const float* att_edge  = (const float*)d_in[8];
    const float* gat_bias  = (const float*)d_in[9];
    const float* ln_gamma  = (const float*)d_in[10];
    const float* ln_beta   = (const float*)d_in[11];
    const float* W_out     = (const float*)d_in[12];
    const float* b_out     = (const float*)d_in[13];
    const float* ln_og     = (const float*)d_in[14];
    const float* ln_ob     = (const float*)d_in[15];
    const float* W_g       = (const float*)d_in[16];
    const float* b_g       = (const float*)d_in[17];
    const float* g_gamma   = (const float*)d_in[18];
    const float* g_beta    = (const float*)d_in[19];
    const int* edge_index  = (const int*)d_in[20];
    const int* batch       = (const int*)d_in[21];
    float* out = (float*)d_out;

    float* ws              = (float*)d_ws;
    unsigned int* h_bf     = (unsigned int*)ws;               // N*64
    unsigned int* xs       = h_bf + (size_t)N_NODES * 64;     // N*64
    unsigned int* x_bf     = xs + (size_t)N_NODES * 64;       // N*16
    float* a_s             = (float*)(x_bf + (size_t)N_NODES * 16);  // N*4
    float* a_d             = a_s + (size_t)N_NODES * 4;       // N*4
    float* csr_ae          = a_d + (size_t)N_NODES * 4;       // 2*E2*4
    unsigned short* gwt    = (unsigned short*)(csr_ae + (size_t)2 * E2 * 4);  // 73728 shorts
    float* meta            = (float*)(gwt + GWT_TOT);         // 152
    float* gsum            = meta + 152;                      // 1024
    float* gcnt            = gsum + NGRAPH * EMB;             // 8
    int*   off             = (int*)(gcnt + NGRAPH);           // N+2 (padded even)
    int*   csr_src         = off + N_NODES + 2;               // E2
    int2*  brec            = (int2*)(csr_src + E2);           // E2 int2 (8B-aligned)
    int*   hist            = (int*)(brec + E2);               // NBUCK*NCHUNK
    int*   btot            = hist + NBUCK * NCHUNK;           // NBUCK
    int*   bucket_base     = btot + NBUCK;                    // NBUCK+1
    // perm (int2[E2] = 6.8MB) aliases xs: xs is first written by dense layer 0,
    // which runs after compute_ae has consumed perm. 16B-aligned.
    int2*  perm            = (int2*)xs;
    // total ~17.1M words = 68.3 MB (fits workspace)

    zero_kernel<<<8, 256, 0, stream>>>(meta, 152 + NGRAPH * EMB + NGRAPH);
    mega_kernel<<<NCHUNK + 512 + NB32 + 36, 256, 0, stream>>>(
        edge_index, edge_attr, x, W_in, b_in, W_src, W_out, W_g,
        hist, meta, h_bf, x_bf, gwt);

    bucket_scan_kernel<<<NBUCK, 256, 0, stream>>>(hist, btot);
    base_prep_kernel<<<1, 256, 0, stream>>>(btot, bucket_base, W_edge, att_edge, meta);
    scatter_bucket_kernel<<<NCHUNK, 256, 0, stream>>>(edge_index, hist, bucket_base, brec);
    local_sort_kernel<<<NBUCK, 512, 0, stream>>>(bucket_base, brec, off, perm);
    compute_ae_kernel<<<EB, 256, 0, stream>>>(perm, edge_attr, meta,
                                              csr_src, csr_ae, csr_ae + (size_t)E2 * 4);

    for (int l = 0; l < NLAYER; l++) {
        dense_mfma_kernel<GAT_IN, 0><<<NB64, 256, 0, stream>>>(
            x_bf, h_bf, gwt + (l ? GWT_SRC1 : GWT_SRC0), nullptr,
            att_src + (size_t)l * EMB, att_dst + (size_t)l * EMB, nullptr,
            xs, a_s, a_d, nullptr, nullptr, nullptr);
        gat_gather_kernel<<<N_NODES / 4, 256, 0, stream>>>(
            off, csr_src, csr_ae + (size_t)l * E2 * 4, xs, a_s, a_d,
            gat_bias + (size_t)l * EMB, ln_gamma + (size_t)l * EMB,
            ln_beta + (size_t)l * EMB, h_bf);
    }

    dense_mfma_kernel<EMB, 1><<<NB64, 256, 0, stream>>>(
        nullptr, h_bf, gwt + GWT_OUT, b_out, ln_og, ln_ob, nullptr,
        nullptr, nullptr, nullptr, out, nullptr, nullptr);
    dense_mfma_kernel<EMB, 2><<<NB64, 256, 0, stream>>>(
        nullptr, h_bf, gwt + GWT_G, b_g, g_gamma, g_beta, batch,
        nullptr, nullptr, nullptr, nullptr, gsum, gcnt);
    graph_out_kernel<<<4, 256, 0, stream>>>(gsum, gcnt, out);
}